// Round 8
// baseline (279.356 us; speedup 1.0000x reference)
//
#include <hip/hip_runtime.h>
#include <math.h>

typedef _Float16 half8v __attribute__((ext_vector_type(8)));
typedef _Float16 half4v __attribute__((ext_vector_type(4)));
typedef _Float16 half2v __attribute__((ext_vector_type(2)));
typedef float float4v __attribute__((ext_vector_type(4)));

// ---- problem constants ----
#define BB    4096
#define INV_ALPHA (1.0f/0.9f)

// ---- workspace float offsets ----
#define WS_CCW  0
#define WS_CCS  64
#define WS_LAM  128
#define WS_CNT  132          // uint finish-counter for mode-0 last-block
#define WS_XMX2 133          // max(x2) for step 2 (written by last block)
#define WS_PM   256          // 256 block-maxes of xm
#define WS_XM   512
#define WS_X    (WS_XM + BB)     // 4608
#define WS_X2   (WS_X + BB)      // 8704
#define WS_A1   (WS_X2 + BB)     // 12800 : step-1 I1 accumulators
#define WS_A2   (WS_A1 + BB)     // 16896 : step-1 I2 accumulators (ends 20992)
#define WS_H    24576   // halfs region starts at byte 98304
// half offsets within WS_H
#define H_NET   8192
#define H_W2    4096
#define H_W0    16384   // + net*2048 : [64 j][32 k] zero-padded
#define H_W3    20480   // + net*64

#if defined(__has_builtin)
#if __has_builtin(__builtin_amdgcn_rcpf)
#define FRCP(x) __builtin_amdgcn_rcpf(x)
#endif
#if __has_builtin(__builtin_amdgcn_exp2f)
#define FEXP2(x) __builtin_amdgcn_exp2f(x)
#endif
#if __has_builtin(__builtin_amdgcn_logf)
#define FLOG2(x) __builtin_amdgcn_logf(x)
#endif
#endif
#ifndef FRCP
#define FRCP(x) (1.0f / (x))
#endif
#ifndef FEXP2
#define FEXP2(x) exp2f(x)
#endif
#ifndef FLOG2
#define FLOG2(x) log2f(x)
#endif

// act: 64 rows x 64 halfs, 16B column-blocks XOR-swizzled by row
__device__ __forceinline__ int swz(int row, int cb) {
    return (row << 6) + (((cb ^ (row & 7)) & 7) << 3);
}

// relu + pack f32x4 -> f16x4
__device__ __forceinline__ half4v pk_relu4(float4v c) {
#if defined(__has_builtin) && __has_builtin(__builtin_amdgcn_cvt_pkrtz)
    half2v a = __builtin_bit_cast(half2v,
        __builtin_amdgcn_cvt_pkrtz(fmaxf(c[0], 0.0f), fmaxf(c[1], 0.0f)));
    half2v b = __builtin_bit_cast(half2v,
        __builtin_amdgcn_cvt_pkrtz(fmaxf(c[2], 0.0f), fmaxf(c[3], 0.0f)));
    half4v o; o[0] = a[0]; o[1] = a[1]; o[2] = b[0]; o[3] = b[1];
    return o;
#else
    half4v o;
    o[0] = (_Float16)fmaxf(c[0], 0.0f); o[1] = (_Float16)fmaxf(c[1], 0.0f);
    o[2] = (_Float16)fmaxf(c[2], 0.0f); o[3] = (_Float16)fmaxf(c[3], 0.0f);
    return o;
#endif
}

// integrand tail: ELU+1 -> 5 powers -> 1/(f+1) dot Wf -> relu
__device__ __forceinline__ float tail5(float y,
        float p0, float p1, float p2, float p3, float p4,
        float wf0, float wf1, float wf2, float wf3, float wf4) {
    if (y <= 0.0f) y = FEXP2(y * 1.44269504f) - 1.0f;   // elu
    float z = y + 1.0f;
    float lg = FLOG2(z);
    float g = wf0 * FRCP(FEXP2(p0 * lg) + 1.0f)
            + wf1 * FRCP(FEXP2(p1 * lg) + 1.0f)
            + wf2 * FRCP(FEXP2(p2 * lg) + 1.0f)
            + wf3 * FRCP(FEXP2(p3 * lg) + 1.0f)
            + wf4 * FRCP(FEXP2(p4 * lg) + 1.0f);
    return fmaxf(g, 0.0f);
}

// ---- fused setup: xm + maxes | weight repack | CC + lam | zero accumulators ----
__global__ void k_setup(const float* __restrict__ x_, const float* __restrict__ lw,
                        const float* __restrict__ sp,
                        const float* __restrict__ f1W0, const float* __restrict__ f1W1,
                        const float* __restrict__ f1W2, const float* __restrict__ f1W3,
                        const float* __restrict__ f2W0, const float* __restrict__ f2W1,
                        const float* __restrict__ f2W2, const float* __restrict__ f2W3,
                        float* __restrict__ ws, float* __restrict__ out) {
    _Float16* wh = (_Float16*)(ws + WS_H);
    const int blk = blockIdx.x, tid = threadIdx.x;
    if (blk < 256) {
        int wave = tid >> 6, lane = tid & 63;
        float vmax = -1e30f;
        for (int r = 0; r < 4; ++r) {
            int row = blk * 16 + wave * 4 + r;
            float v = 0.0f;
            for (int i = lane; i < 100; i += 64) v = fmaf(x_[row * 100 + i], lw[i], v);
            #pragma unroll
            for (int off = 32; off > 0; off >>= 1) v += __shfl_xor(v, off, 64);
            if (lane == 0) ws[WS_XM + row] = v;
            vmax = fmaxf(vmax, v);
        }
        __shared__ float sm[4];
        if (lane == 0) sm[wave] = vmax;
        __syncthreads();
        if (tid == 0)
            ws[WS_PM + blk] = fmaxf(fmaxf(sm[0], sm[1]), fmaxf(sm[2], sm[3]));
    } else if (blk < 272) {
        int t = (blk - 256) * 256 + tid;       // 0..4095
        wh[t]                = (_Float16)f1W1[t];
        wh[H_W2 + t]         = (_Float16)f1W2[t];
        wh[H_NET + t]        = (_Float16)f2W1[t];
        wh[H_NET + H_W2 + t] = (_Float16)f2W2[t];
        if (t < 2048) {
            int j = t >> 5, k = t & 31;
            wh[H_W0 + t]        = (k < 5) ? (_Float16)f1W0[j * 5 + k] : (_Float16)0.0f;
            wh[H_W0 + 2048 + t] = (k < 5) ? (_Float16)f2W0[j * 5 + k] : (_Float16)0.0f;
        }
        if (t < 64) {
            wh[H_W3 + t]      = (_Float16)f1W3[t];
            wh[H_W3 + 64 + t] = (_Float16)f2W3[t];
        }
    } else if (blk == 272) {
        if (tid == 64) ws[WS_LAM] = 1.0f / (1.0f + expf(-sp[0]));
        if (tid == 63) ws[WS_CNT] = 0.0f;           // uint 0
        if (tid <= 50) {
            int s = tid;
            ws[WS_CCS + s] = cospif((float)s / 50.0f);
            float acc = 0.0f;
            for (int a = 0; a <= 50; ++a) {
                float w;
                if (a == 0) w = 1.0f;
                else if ((a & 1) == 0) w = 2.0f / (1.0f - (float)(a * a));
                else continue;
                float l;
                if (s == 0) l = 0.5f;
                else {
                    int m = (a * s) % 100;
                    l = cospif((float)m / 50.0f);
                    if (s == 50) l *= 0.5f;
                }
                acc += l * 0.04f * w;
            }
            ws[WS_CCW + s] = acc;
        }
    } else if (blk < 305) {
        // zero step-2 accumulation targets: out[0..BB) and out[2BB..3BB)
        int t = (blk - 273) * 256 + tid;       // 0..8191
        out[t < BB ? t : BB + t] = 0.0f;
    } else {
        // zero step-1 accumulators ws A1 (then A2, contiguous)
        int t = (blk - 305) * 256 + tid;       // 0..8191
        ws[WS_A1 + t] = 0.0f;
    }
}

// 24-waves-per-group, 3-blocks/CU resident (LDS 49.75 KB x 3 = 149.25 <= 160).
// Weights in LDS fragment-major (spill-free, round-6 WIN). Block b (0..767):
// group g = b/6 (0..127), wave w = (b%6)*4 + wloc (0..23). Group g owns items
// [(g&63)*64,+64) of net (g>=64 ? f2:f1). Wave w takes s = w, w+24
// [, w+48 if w<3] -> s-cover 0..50 exact. mode1 w==23 f1 wave computes
// out_first in an extra slot. Step-1 (mode 0) accumulates into ws A1/A2;
// the LAST mode-0 block (device-scope counter) folds k_pre: computes
// x/x2/max(x2) for step 2. Step-2 (mode 1) accumulates into out.
__global__ __launch_bounds__(256, 3) void k_int(
    int mode, float* __restrict__ ws, const float* __restrict__ h_,
    const float* __restrict__ f1b0, const float* __restrict__ f1b1,
    const float* __restrict__ f1b2, const float* __restrict__ f1b3,
    const float* __restrict__ f1Wf,
    const float* __restrict__ f2b0, const float* __restrict__ f2b1,
    const float* __restrict__ f2b2, const float* __restrict__ f2b3,
    const float* __restrict__ f2Wf,
    float* __restrict__ out)
{
    __shared__ _Float16 act[4 * 64 * 64];   // 32 KB: per-wave slices
    __shared__ _Float16 w0f[4 * 16 * 8];    // 1 KB  : L0 frags (q==0 only)
    __shared__ _Float16 w1f[512 * 8];       // 8 KB  : L1 frags, frag-major
    __shared__ _Float16 w2f[512 * 8];       // 8 KB  : L2 frags, frag-major
    __shared__ float bl[192];               // biases: [layer*64 + feat]

    const int tid = threadIdx.x;
    const int blk = blockIdx.x;
    const int wloc = tid >> 6;
    const int lane = tid & 63;
    const int lo = lane & 15, q = lane >> 4;

    const int g = blk / 6;                // 0..127
    const int w = (blk - g * 6) * 4 + wloc;   // 0..23
    const bool u2 = (g >= 64);
    const int base = (g & 63) << 6;
    const bool of_wave = (mode != 0) && (!u2) && (w == 23);

    const float* xm = ws + WS_XM;
    const float* xarr = ws + WS_X;
    const float* x2arr = ws + WS_X2;
    const _Float16* wh = (const _Float16*)(ws + WS_H);
    const float lam = ws[WS_LAM];
    const float oml = 1.0f - lam;

    const _Float16* W0h = wh + H_W0 + (u2 ? 2048 : 0);
    const _Float16* W1h = wh + (u2 ? H_NET : 0);
    const _Float16* W2h = W1h + H_W2;
    const _Float16* W3h = wh + H_W3 + (u2 ? 64 : 0);
    const float* B0 = u2 ? f2b0 : f1b0;
    const float* B1 = u2 ? f2b1 : f1b1;
    const float* B2 = u2 ? f2b2 : f1b2;
    const float* B3 = u2 ? f2b3 : f1b3;
    const float* WF = u2 ? f2Wf : f1Wf;
    const float p0 = u2 ? 1.5f : 1.1f;
    const float p1 = u2 ? 2.0f : 1.1f;
    const float p2 = u2 ? 2.5f : 1.5f;
    const float p3 = u2 ? 3.0f : 2.0f;
    const float p4 = u2 ? 3.5f : 2.5f;

    // ---- stage weights -> LDS, fragment-major (f = (m*2+kb)*64 + lane) ----
    #pragma unroll
    for (int f = tid; f < 512; f += 256) {
        int fm = f >> 7, fkb = (f >> 6) & 1, fl = f & 63;
        int flo = fl & 15, fq = fl >> 4;
        *(half8v*)(w1f + f * 8) =
            *(const half8v*)(W1h + (16 * fm + flo) * 64 + fkb * 32 + fq * 8);
        *(half8v*)(w2f + f * 8) =
            *(const half8v*)(W2h + (16 * fm + flo) * 64 + fkb * 32 + fq * 8);
    }
    if (tid < 64) {
        int fm = tid >> 4, flo = tid & 15;
        *(half8v*)(w0f + tid * 8) = *(const half8v*)(W0h + (16 * fm + flo) * 32);
    }
    if (tid < 192)
        bl[tid] = (tid < 64) ? B0[tid] : (tid < 128) ? B1[tid - 64] : B2[tid - 128];

    // ---- small per-lane pins (while staging is in flight) ----
    half4v w3r[4];
    #pragma unroll
    for (int m = 0; m < 4; ++m)
        w3r[m] = *(const half4v*)(W3h + 16 * m + 4 * q);
    const float B3s = B3[0];
    const float wf0 = WF[0], wf1 = WF[1], wf2 = WF[2], wf3 = WF[3], wf4 = WF[4];

    half8v zf;                            // zero fragment (shared)
    #pragma unroll
    for (int t2 = 0; t2 < 8; ++t2) zf[t2] = (_Float16)0.0f;

    float xr_r[4], x2_r[4];
    half8v tpl[4];                        // pre-packed B template (h in halfs)
    #pragma unroll
    for (int n = 0; n < 4; ++n) {
        int idx = base + 16 * n + lo;
        xr_r[n] = mode ? (u2 ? x2arr[idx] : xarr[idx]) : oml * xm[idx];
        float4 h4 = ((const float4*)h_)[idx];
        half8v e = zf;
        e[1] = (_Float16)h4.x; e[2] = (_Float16)h4.y;
        e[3] = (_Float16)h4.z; e[4] = (_Float16)h4.w;
        tpl[n] = (q == 0) ? e : zf;
        x2_r[n] = 0.0f;
    }
    if (of_wave) {
        #pragma unroll
        for (int n = 0; n < 4; ++n) x2_r[n] = x2arr[base + 16 * n + lo];
    }

    float xmax = 0.0f;
    if (u2) {
        if (mode) {
            xmax = ws[WS_XMX2] + 10.0f;     // scalar, from mode-0 last block
        } else {
            const float* pm = ws + WS_PM;
            float v = fmaxf(fmaxf(pm[lane], pm[lane + 64]),
                            fmaxf(pm[lane + 128], pm[lane + 192]));
            #pragma unroll
            for (int off = 32; off > 0; off >>= 1) v = fmaxf(v, __shfl_xor(v, off, 64));
            xmax = oml * v + 10.0f;
        }
    }

    __syncthreads();                      // weights/biases staged

    _Float16* actw = act + (wloc << 12);  // private 4096-half slice
    const int np = (w < 3 || of_wave) ? 3 : 2;
    float acc = 0.0f;

    #pragma clang loop unroll(disable)
    for (int p = 0; p < np; ++p) {
        const bool of_iter = of_wave && (p == 2);
        float t = 0.0f, ccw_s = 0.0f;
        if (!of_iter) {
            int s = w + 24 * p;                     // <= 50 by construction
            t = (ws[WS_CCS + s] + 1.0f) * 0.5f;
            ccw_s = ws[WS_CCW + s];
        }

        // build B-operand for layer 0 from template (q==0 lanes carry k=0..4)
        half8v Bf0[4];
        #pragma unroll
        for (int n = 0; n < 4; ++n) {
            float xin;
            if (of_iter) xin = x2_r[n];
            else if (u2) xin = fmaf(t, xmax - xr_r[n], xr_r[n]);
            else         xin = xr_r[n] * t;
            half8v b = tpl[n];
            b[0] = (_Float16)((q == 0) ? xin : 0.0f);
            Bf0[n] = b;
        }

        // ---- layer 0: A-frag from LDS (broadcast reads, q==0 rows only) ----
        #pragma unroll
        for (int m = 0; m < 4; ++m) {
            half8v a0 = (q == 0) ? *(const half8v*)(w0f + (m * 16 + lo) * 8) : zf;
            float4v b0 = *(const float4v*)(bl + 16 * m + 4 * q);
            #pragma unroll
            for (int n = 0; n < 4; ++n) {
                float4v c = __builtin_amdgcn_mfma_f32_16x16x32_f16(a0, Bf0[n], b0, 0, 0, 0);
                *(half4v*)(actw + swz(16 * n + lo, 2 * m + (q >> 1)) + 4 * (q & 1)) = pk_relu4(c);
            }
        }

        // ---- layer 1: A-frags lane-consecutive from LDS ----
        {
            half8v Bf[2][4];
            #pragma unroll
            for (int kb = 0; kb < 2; ++kb)
                #pragma unroll
                for (int n = 0; n < 4; ++n)
                    Bf[kb][n] = *(const half8v*)(actw + swz(16 * n + lo, 4 * kb + q));
            #pragma unroll
            for (int m = 0; m < 4; ++m) {
                half8v a10 = *(const half8v*)(w1f + ((m * 2 + 0) * 64 + lane) * 8);
                half8v a11 = *(const half8v*)(w1f + ((m * 2 + 1) * 64 + lane) * 8);
                float4v b1 = *(const float4v*)(bl + 64 + 16 * m + 4 * q);
                #pragma unroll
                for (int n = 0; n < 4; ++n) {
                    float4v c = __builtin_amdgcn_mfma_f32_16x16x32_f16(a10, Bf[0][n], b1, 0, 0, 0);
                    c = __builtin_amdgcn_mfma_f32_16x16x32_f16(a11, Bf[1][n], c, 0, 0, 0);
                    *(half4v*)(actw + swz(16 * n + lo, 2 * m + (q >> 1)) + 4 * (q & 1)) = pk_relu4(c);
                }
            }
        }

        // ---- layer 2 with fused W3-dot ----
        float part[4] = {0.0f, 0.0f, 0.0f, 0.0f};
        {
            half8v Bf[2][4];
            #pragma unroll
            for (int kb = 0; kb < 2; ++kb)
                #pragma unroll
                for (int n = 0; n < 4; ++n)
                    Bf[kb][n] = *(const half8v*)(actw + swz(16 * n + lo, 4 * kb + q));
            #pragma unroll
            for (int m = 0; m < 4; ++m) {
                half8v a20 = *(const half8v*)(w2f + ((m * 2 + 0) * 64 + lane) * 8);
                half8v a21 = *(const half8v*)(w2f + ((m * 2 + 1) * 64 + lane) * 8);
                float4v b2 = *(const float4v*)(bl + 128 + 16 * m + 4 * q);
                #pragma unroll
                for (int n = 0; n < 4; ++n) {
                    float4v c = __builtin_amdgcn_mfma_f32_16x16x32_f16(a20, Bf[0][n], b2, 0, 0, 0);
                    c = __builtin_amdgcn_mfma_f32_16x16x32_f16(a21, Bf[1][n], c, 0, 0, 0);
                    #pragma unroll
                    for (int e = 0; e < 4; ++e)
                        part[n] = fmaf((float)w3r[m][e], fmaxf(c[e], 0.0f), part[n]);
                }
            }
        }

        // complete each row's dot across quads; lane keeps its own row (=lane)
        #pragma unroll
        for (int n = 0; n < 4; ++n) {
            part[n] += __shfl_xor(part[n], 16, 64);
            part[n] += __shfl_xor(part[n], 32, 64);
        }
        float y = B3s + (q == 0 ? part[0] : q == 1 ? part[1] : q == 2 ? part[2] : part[3]);

        float val = tail5(y, p0, p1, p2, p3, p4, wf0, wf1, wf2, wf3, wf4);

        if (of_iter) out[BB + base + lane] = val;
        else         acc = fmaf(ccw_s, val, acc);
    }

    // ---- per-item epilogue: lane owns item base+lane (row 16q+lo == lane) ----
    const float x_l = (q == 0 ? xr_r[0] : q == 1 ? xr_r[1] : q == 2 ? xr_r[2] : xr_r[3]);
    if (mode == 0) {
        if (!u2) atomicAdd(ws + WS_A1 + base + lane, acc * x_l * 0.5f);
        else     atomicAdd(ws + WS_A2 + base + lane, acc * (xmax - x_l) * 0.5f * INV_ALPHA);

        // ---- folded k_pre: last block computes x/x2/max(x2) for step 2 ----
        __threadfence();
        __syncthreads();
        __shared__ bool last;
        if (tid == 0) {
            unsigned* cnt = (unsigned*)(ws + WS_CNT);
            last = (atomicAdd(cnt, 1u) == (unsigned)(gridDim.x - 1));
        }
        __syncthreads();
        if (last) {
            __threadfence();
            float vmax = -1e30f;
            for (int i = tid; i < BB; i += 256) {
                float a1 = __hip_atomic_load(ws + WS_A1 + i, __ATOMIC_RELAXED,
                                             __HIP_MEMORY_SCOPE_AGENT);
                float a2 = __hip_atomic_load(ws + WS_A2 + i, __ATOMIC_RELAXED,
                                             __HIP_MEMORY_SCOPE_AGENT);
                float m0 = xm[i];
                float xv  = oml * m0 + lam * a1;
                float x2v = oml * m0 + lam * a2;
                ws[WS_X + i]  = xv;
                ws[WS_X2 + i] = x2v;
                vmax = fmaxf(vmax, x2v);
            }
            #pragma unroll
            for (int off = 32; off > 0; off >>= 1)
                vmax = fmaxf(vmax, __shfl_xor(vmax, off, 64));
            __shared__ float rm[4];
            if (lane == 0) rm[wloc] = vmax;
            __syncthreads();
            if (tid == 0)
                ws[WS_XMX2] = fmaxf(fmaxf(rm[0], rm[1]), fmaxf(rm[2], rm[3]));
        }
    } else {
        if (!u2) atomicAdd(out + base + lane, acc * x_l * 0.5f);
        else     atomicAdd(out + 2 * BB + base + lane,
                           acc * (xmax - x_l) * 0.5f * INV_ALPHA);
    }
}

extern "C" void kernel_launch(void* const* d_in, const int* in_sizes, int n_in,
                              void* d_out, int out_size, void* d_ws, size_t ws_size,
                              hipStream_t stream) {
    const float* x_  = (const float*)d_in[0];
    const float* h_  = (const float*)d_in[1];
    const float* lw  = (const float*)d_in[2];
    const float* sp  = (const float*)d_in[3];
    const float* f1W0 = (const float*)d_in[4];   const float* f1b0 = (const float*)d_in[5];
    const float* f1W1 = (const float*)d_in[6];   const float* f1b1 = (const float*)d_in[7];
    const float* f1W2 = (const float*)d_in[8];   const float* f1b2 = (const float*)d_in[9];
    const float* f1W3 = (const float*)d_in[10];  const float* f1b3 = (const float*)d_in[11];
    const float* f1Wf = (const float*)d_in[12];
    const float* f2W0 = (const float*)d_in[13];  const float* f2b0 = (const float*)d_in[14];
    const float* f2W1 = (const float*)d_in[15];  const float* f2b1 = (const float*)d_in[16];
    const float* f2W2 = (const float*)d_in[17];  const float* f2b2 = (const float*)d_in[18];
    const float* f2W3 = (const float*)d_in[19];  const float* f2b3 = (const float*)d_in[20];
    const float* f2Wf = (const float*)d_in[21];
    float* out = (float*)d_out;
    float* ws  = (float*)d_ws;

    k_setup<<<337, 256, 0, stream>>>(x_, lw, sp,
                                     f1W0, f1W1, f1W2, f1W3,
                                     f2W0, f2W1, f2W2, f2W3, ws, out);
    k_int<<<768, 256, 0, stream>>>(0, ws, h_,
        f1b0, f1b1, f1b2, f1b3, f1Wf, f2b0, f2b1, f2b2, f2b3, f2Wf, out);
    k_int<<<768, 256, 0, stream>>>(1, ws, h_,
        f1b0, f1b1, f1b2, f1b3, f1Wf, f2b0, f2b1, f2b2, f2b3, f2Wf, out);
}

// Round 9
// 165.049 us; speedup vs baseline: 1.6926x; 1.6926x over previous
//
#include <hip/hip_runtime.h>
#include <math.h>

typedef _Float16 half8v __attribute__((ext_vector_type(8)));
typedef _Float16 half4v __attribute__((ext_vector_type(4)));
typedef _Float16 half2v __attribute__((ext_vector_type(2)));
typedef float float4v __attribute__((ext_vector_type(4)));

// ---- problem constants ----
#define BB    4096
#define INV_ALPHA (1.0f/0.9f)

// ---- workspace float offsets ----
#define WS_CCW  0
#define WS_CCS  64
#define WS_LAM  128
#define WS_CNT  132          // uint finish-counter for mode-0 last-block
#define WS_XMX2 133          // max(x2) for step 2 (written by last block)
#define WS_PM   256          // 256 block-maxes of xm
#define WS_XM   512
#define WS_X    (WS_XM + BB)     // 4608
#define WS_X2   (WS_X + BB)      // 8704
#define WS_A1   (WS_X2 + BB)     // 12800 : step-1 I1 accumulators
#define WS_A2   (WS_A1 + BB)     // 16896 : step-1 I2 accumulators (ends 20992)
#define WS_H    24576   // halfs region starts at byte 98304
// half offsets within WS_H
#define H_NET   8192
#define H_W2    4096
#define H_W0    16384   // + net*2048 : [64 j][32 k] zero-padded
#define H_W3    20480   // + net*64

#if defined(__has_builtin)
#if __has_builtin(__builtin_amdgcn_rcpf)
#define FRCP(x) __builtin_amdgcn_rcpf(x)
#endif
#if __has_builtin(__builtin_amdgcn_exp2f)
#define FEXP2(x) __builtin_amdgcn_exp2f(x)
#endif
#if __has_builtin(__builtin_amdgcn_logf)
#define FLOG2(x) __builtin_amdgcn_logf(x)
#endif
#endif
#ifndef FRCP
#define FRCP(x) (1.0f / (x))
#endif
#ifndef FEXP2
#define FEXP2(x) exp2f(x)
#endif
#ifndef FLOG2
#define FLOG2(x) log2f(x)
#endif

// act: 64 rows x 64 halfs, 16B column-blocks XOR-swizzled by row
__device__ __forceinline__ int swz(int row, int cb) {
    return (row << 6) + (((cb ^ (row & 7)) & 7) << 3);
}

// relu + pack f32x4 -> f16x4
__device__ __forceinline__ half4v pk_relu4(float4v c) {
#if defined(__has_builtin) && __has_builtin(__builtin_amdgcn_cvt_pkrtz)
    half2v a = __builtin_bit_cast(half2v,
        __builtin_amdgcn_cvt_pkrtz(fmaxf(c[0], 0.0f), fmaxf(c[1], 0.0f)));
    half2v b = __builtin_bit_cast(half2v,
        __builtin_amdgcn_cvt_pkrtz(fmaxf(c[2], 0.0f), fmaxf(c[3], 0.0f)));
    half4v o; o[0] = a[0]; o[1] = a[1]; o[2] = b[0]; o[3] = b[1];
    return o;
#else
    half4v o;
    o[0] = (_Float16)fmaxf(c[0], 0.0f); o[1] = (_Float16)fmaxf(c[1], 0.0f);
    o[2] = (_Float16)fmaxf(c[2], 0.0f); o[3] = (_Float16)fmaxf(c[3], 0.0f);
    return o;
#endif
}

// integrand tail: ELU+1 -> 5 powers -> 1/(f+1) dot Wf -> relu
__device__ __forceinline__ float tail5(float y,
        float p0, float p1, float p2, float p3, float p4,
        float wf0, float wf1, float wf2, float wf3, float wf4) {
    if (y <= 0.0f) y = FEXP2(y * 1.44269504f) - 1.0f;   // elu
    float z = y + 1.0f;
    float lg = FLOG2(z);
    float g = wf0 * FRCP(FEXP2(p0 * lg) + 1.0f)
            + wf1 * FRCP(FEXP2(p1 * lg) + 1.0f)
            + wf2 * FRCP(FEXP2(p2 * lg) + 1.0f)
            + wf3 * FRCP(FEXP2(p3 * lg) + 1.0f)
            + wf4 * FRCP(FEXP2(p4 * lg) + 1.0f);
    return fmaxf(g, 0.0f);
}

// ---- fused setup: xm + maxes | weight repack | CC + lam | zero accumulators ----
__global__ void k_setup(const float* __restrict__ x_, const float* __restrict__ lw,
                        const float* __restrict__ sp,
                        const float* __restrict__ f1W0, const float* __restrict__ f1W1,
                        const float* __restrict__ f1W2, const float* __restrict__ f1W3,
                        const float* __restrict__ f2W0, const float* __restrict__ f2W1,
                        const float* __restrict__ f2W2, const float* __restrict__ f2W3,
                        float* __restrict__ ws, float* __restrict__ out) {
    _Float16* wh = (_Float16*)(ws + WS_H);
    const int blk = blockIdx.x, tid = threadIdx.x;
    if (blk < 256) {
        int wave = tid >> 6, lane = tid & 63;
        float vmax = -1e30f;
        for (int r = 0; r < 4; ++r) {
            int row = blk * 16 + wave * 4 + r;
            float v = 0.0f;
            for (int i = lane; i < 100; i += 64) v = fmaf(x_[row * 100 + i], lw[i], v);
            #pragma unroll
            for (int off = 32; off > 0; off >>= 1) v += __shfl_xor(v, off, 64);
            if (lane == 0) ws[WS_XM + row] = v;
            vmax = fmaxf(vmax, v);
        }
        __shared__ float sm[4];
        if (lane == 0) sm[wave] = vmax;
        __syncthreads();
        if (tid == 0)
            ws[WS_PM + blk] = fmaxf(fmaxf(sm[0], sm[1]), fmaxf(sm[2], sm[3]));
    } else if (blk < 272) {
        int t = (blk - 256) * 256 + tid;       // 0..4095
        wh[t]                = (_Float16)f1W1[t];
        wh[H_W2 + t]         = (_Float16)f1W2[t];
        wh[H_NET + t]        = (_Float16)f2W1[t];
        wh[H_NET + H_W2 + t] = (_Float16)f2W2[t];
        if (t < 2048) {
            int j = t >> 5, k = t & 31;
            wh[H_W0 + t]        = (k < 5) ? (_Float16)f1W0[j * 5 + k] : (_Float16)0.0f;
            wh[H_W0 + 2048 + t] = (k < 5) ? (_Float16)f2W0[j * 5 + k] : (_Float16)0.0f;
        }
        if (t < 64) {
            wh[H_W3 + t]      = (_Float16)f1W3[t];
            wh[H_W3 + 64 + t] = (_Float16)f2W3[t];
        }
    } else if (blk == 272) {
        if (tid == 64) ws[WS_LAM] = 1.0f / (1.0f + expf(-sp[0]));
        if (tid == 63) *(unsigned*)(ws + WS_CNT) = 0u;
        if (tid <= 50) {
            int s = tid;
            ws[WS_CCS + s] = cospif((float)s / 50.0f);
            float acc = 0.0f;
            for (int a = 0; a <= 50; ++a) {
                float w;
                if (a == 0) w = 1.0f;
                else if ((a & 1) == 0) w = 2.0f / (1.0f - (float)(a * a));
                else continue;
                float l;
                if (s == 0) l = 0.5f;
                else {
                    int m = (a * s) % 100;
                    l = cospif((float)m / 50.0f);
                    if (s == 50) l *= 0.5f;
                }
                acc += l * 0.04f * w;
            }
            ws[WS_CCW + s] = acc;
        }
    } else if (blk < 305) {
        // zero step-2 accumulation targets: out[0..BB) and out[2BB..3BB)
        int t = (blk - 273) * 256 + tid;       // 0..8191
        out[t < BB ? t : BB + t] = 0.0f;
    } else {
        // zero step-1 accumulators ws A1 (then A2, contiguous)
        int t = (blk - 305) * 256 + tid;       // 0..8191
        ws[WS_A1 + t] = 0.0f;
    }
}

// Round-6 WIN structure (16 waves/group, __launch_bounds__(256,2), grid 512,
// LDS fragment-major weights -> no spill; VGPR ~128 is the required budget,
// NEVER squeeze it via launch bounds) + folded k_pre: step-1 (mode 0)
// accumulates into ws A1/A2; the LAST mode-0 block (device counter) computes
// x/x2/max(x2) for step 2. Step-2 (mode 1) accumulates into out and reads
// xmax as a single scalar. Block b: group g = b>>2 (0..127), wave
// w = (b&3)*4+wloc (0..15). Group g owns items [(g&63)*64,+64) of net
// (g>=64 ? f2:f1). Wave w takes s = w, w+16, w+32 [, w+48 if w<3]; the
// w==15 f1 wave in mode 1 computes out_first in its dead 4th slot.
__global__ __launch_bounds__(256, 2) void k_int(
    int mode, float* __restrict__ ws, const float* __restrict__ h_,
    const float* __restrict__ f1b0, const float* __restrict__ f1b1,
    const float* __restrict__ f1b2, const float* __restrict__ f1b3,
    const float* __restrict__ f1Wf,
    const float* __restrict__ f2b0, const float* __restrict__ f2b1,
    const float* __restrict__ f2b2, const float* __restrict__ f2b3,
    const float* __restrict__ f2Wf,
    float* __restrict__ out)
{
    __shared__ _Float16 act[4 * 64 * 64];   // 32 KB: per-wave slices
    __shared__ _Float16 w0f[4 * 16 * 8];    // 1 KB  : L0 frags (q==0 only)
    __shared__ _Float16 w1f[512 * 8];       // 8 KB  : L1 frags, frag-major
    __shared__ _Float16 w2f[512 * 8];       // 8 KB  : L2 frags, frag-major
    __shared__ float bl[192];               // biases: [layer*64 + feat]

    const int tid = threadIdx.x;
    const int blk = blockIdx.x;
    const int wloc = tid >> 6;
    const int lane = tid & 63;
    const int lo = lane & 15, q = lane >> 4;

    const int g = blk >> 2;               // 0..127
    const int w = (blk & 3) * 4 + wloc;   // 0..15
    const bool u2 = (g >= 64);
    const int base = (g & 63) << 6;
    const bool of_wave = (mode != 0) && (!u2) && (w == 15);

    const float* xm = ws + WS_XM;
    const float* xarr = ws + WS_X;
    const float* x2arr = ws + WS_X2;
    const _Float16* wh = (const _Float16*)(ws + WS_H);
    const float lam = ws[WS_LAM];
    const float oml = 1.0f - lam;

    const _Float16* W0h = wh + H_W0 + (u2 ? 2048 : 0);
    const _Float16* W1h = wh + (u2 ? H_NET : 0);
    const _Float16* W2h = W1h + H_W2;
    const _Float16* W3h = wh + H_W3 + (u2 ? 64 : 0);
    const float* B0 = u2 ? f2b0 : f1b0;
    const float* B1 = u2 ? f2b1 : f1b1;
    const float* B2 = u2 ? f2b2 : f1b2;
    const float* B3 = u2 ? f2b3 : f1b3;
    const float* WF = u2 ? f2Wf : f1Wf;
    const float p0 = u2 ? 1.5f : 1.1f;
    const float p1 = u2 ? 2.0f : 1.1f;
    const float p2 = u2 ? 2.5f : 1.5f;
    const float p3 = u2 ? 3.0f : 2.0f;
    const float p4 = u2 ? 3.5f : 2.5f;

    // ---- stage weights -> LDS, fragment-major (f = (m*2+kb)*64 + lane) ----
    #pragma unroll
    for (int f = tid; f < 512; f += 256) {
        int fm = f >> 7, fkb = (f >> 6) & 1, fl = f & 63;
        int flo = fl & 15, fq = fl >> 4;
        *(half8v*)(w1f + f * 8) =
            *(const half8v*)(W1h + (16 * fm + flo) * 64 + fkb * 32 + fq * 8);
        *(half8v*)(w2f + f * 8) =
            *(const half8v*)(W2h + (16 * fm + flo) * 64 + fkb * 32 + fq * 8);
    }
    if (tid < 64) {
        int fm = tid >> 4, flo = tid & 15;
        *(half8v*)(w0f + tid * 8) = *(const half8v*)(W0h + (16 * fm + flo) * 32);
    }
    if (tid < 192)
        bl[tid] = (tid < 64) ? B0[tid] : (tid < 128) ? B1[tid - 64] : B2[tid - 128];

    // ---- small per-lane pins (while staging is in flight) ----
    half4v w3r[4];
    #pragma unroll
    for (int m = 0; m < 4; ++m)
        w3r[m] = *(const half4v*)(W3h + 16 * m + 4 * q);
    const float B3s = B3[0];
    const float wf0 = WF[0], wf1 = WF[1], wf2 = WF[2], wf3 = WF[3], wf4 = WF[4];

    half8v zf;                            // zero fragment (shared)
    #pragma unroll
    for (int t2 = 0; t2 < 8; ++t2) zf[t2] = (_Float16)0.0f;

    float xr_r[4], x2_r[4];
    half8v tpl[4];                        // pre-packed B template (h in halfs)
    #pragma unroll
    for (int n = 0; n < 4; ++n) {
        int idx = base + 16 * n + lo;
        xr_r[n] = mode ? (u2 ? x2arr[idx] : xarr[idx]) : oml * xm[idx];
        float4 h4 = ((const float4*)h_)[idx];
        half8v e = zf;
        e[1] = (_Float16)h4.x; e[2] = (_Float16)h4.y;
        e[3] = (_Float16)h4.z; e[4] = (_Float16)h4.w;
        tpl[n] = (q == 0) ? e : zf;
        x2_r[n] = 0.0f;
    }
    if (of_wave) {
        #pragma unroll
        for (int n = 0; n < 4; ++n) x2_r[n] = x2arr[base + 16 * n + lo];
    }

    float xmax = 0.0f;
    if (u2) {
        if (mode) {
            xmax = ws[WS_XMX2] + 10.0f;     // scalar, from mode-0 last block
        } else {
            const float* pm = ws + WS_PM;
            float v = fmaxf(fmaxf(pm[lane], pm[lane + 64]),
                            fmaxf(pm[lane + 128], pm[lane + 192]));
            #pragma unroll
            for (int off = 32; off > 0; off >>= 1) v = fmaxf(v, __shfl_xor(v, off, 64));
            xmax = oml * v + 10.0f;
        }
    }

    __syncthreads();                      // weights/biases staged

    _Float16* actw = act + (wloc << 12);  // private 4096-half slice
    const int np = (w < 3 || of_wave) ? 4 : 3;
    float acc = 0.0f;

    #pragma clang loop unroll(disable)
    for (int p = 0; p < np; ++p) {
        const bool of_iter = of_wave && (p == 3);
        float t = 0.0f, ccw_s = 0.0f;
        if (!of_iter) {
            int s = w + 16 * p;                     // <= 50 by construction
            t = (ws[WS_CCS + s] + 1.0f) * 0.5f;
            ccw_s = ws[WS_CCW + s];
        }

        // build B-operand for layer 0 from template (q==0 lanes carry k=0..4)
        half8v Bf0[4];
        #pragma unroll
        for (int n = 0; n < 4; ++n) {
            float xin;
            if (of_iter) xin = x2_r[n];
            else if (u2) xin = fmaf(t, xmax - xr_r[n], xr_r[n]);
            else         xin = xr_r[n] * t;
            half8v b = tpl[n];
            b[0] = (_Float16)((q == 0) ? xin : 0.0f);
            Bf0[n] = b;
        }

        // ---- layer 0: A-frag from LDS (broadcast reads, q==0 rows only) ----
        #pragma unroll
        for (int m = 0; m < 4; ++m) {
            half8v a0 = (q == 0) ? *(const half8v*)(w0f + (m * 16 + lo) * 8) : zf;
            float4v b0 = *(const float4v*)(bl + 16 * m + 4 * q);
            #pragma unroll
            for (int n = 0; n < 4; ++n) {
                float4v c = __builtin_amdgcn_mfma_f32_16x16x32_f16(a0, Bf0[n], b0, 0, 0, 0);
                *(half4v*)(actw + swz(16 * n + lo, 2 * m + (q >> 1)) + 4 * (q & 1)) = pk_relu4(c);
            }
        }

        // ---- layer 1: A-frags lane-consecutive from LDS ----
        {
            half8v Bf[2][4];
            #pragma unroll
            for (int kb = 0; kb < 2; ++kb)
                #pragma unroll
                for (int n = 0; n < 4; ++n)
                    Bf[kb][n] = *(const half8v*)(actw + swz(16 * n + lo, 4 * kb + q));
            #pragma unroll
            for (int m = 0; m < 4; ++m) {
                half8v a10 = *(const half8v*)(w1f + ((m * 2 + 0) * 64 + lane) * 8);
                half8v a11 = *(const half8v*)(w1f + ((m * 2 + 1) * 64 + lane) * 8);
                float4v b1 = *(const float4v*)(bl + 64 + 16 * m + 4 * q);
                #pragma unroll
                for (int n = 0; n < 4; ++n) {
                    float4v c = __builtin_amdgcn_mfma_f32_16x16x32_f16(a10, Bf[0][n], b1, 0, 0, 0);
                    c = __builtin_amdgcn_mfma_f32_16x16x32_f16(a11, Bf[1][n], c, 0, 0, 0);
                    *(half4v*)(actw + swz(16 * n + lo, 2 * m + (q >> 1)) + 4 * (q & 1)) = pk_relu4(c);
                }
            }
        }

        // ---- layer 2 with fused W3-dot ----
        float part[4] = {0.0f, 0.0f, 0.0f, 0.0f};
        {
            half8v Bf[2][4];
            #pragma unroll
            for (int kb = 0; kb < 2; ++kb)
                #pragma unroll
                for (int n = 0; n < 4; ++n)
                    Bf[kb][n] = *(const half8v*)(actw + swz(16 * n + lo, 4 * kb + q));
            #pragma unroll
            for (int m = 0; m < 4; ++m) {
                half8v a20 = *(const half8v*)(w2f + ((m * 2 + 0) * 64 + lane) * 8);
                half8v a21 = *(const half8v*)(w2f + ((m * 2 + 1) * 64 + lane) * 8);
                float4v b2 = *(const float4v*)(bl + 128 + 16 * m + 4 * q);
                #pragma unroll
                for (int n = 0; n < 4; ++n) {
                    float4v c = __builtin_amdgcn_mfma_f32_16x16x32_f16(a20, Bf[0][n], b2, 0, 0, 0);
                    c = __builtin_amdgcn_mfma_f32_16x16x32_f16(a21, Bf[1][n], c, 0, 0, 0);
                    #pragma unroll
                    for (int e = 0; e < 4; ++e)
                        part[n] = fmaf((float)w3r[m][e], fmaxf(c[e], 0.0f), part[n]);
                }
            }
        }

        // complete each row's dot across quads; lane keeps its own row (=lane)
        #pragma unroll
        for (int n = 0; n < 4; ++n) {
            part[n] += __shfl_xor(part[n], 16, 64);
            part[n] += __shfl_xor(part[n], 32, 64);
        }
        float y = B3s + (q == 0 ? part[0] : q == 1 ? part[1] : q == 2 ? part[2] : part[3]);

        float val = tail5(y, p0, p1, p2, p3, p4, wf0, wf1, wf2, wf3, wf4);

        if (of_iter) out[BB + base + lane] = val;
        else         acc = fmaf(ccw_s, val, acc);
    }

    // ---- per-item epilogue: lane owns item base+lane (row 16q+lo == lane) ----
    const float x_l = (q == 0 ? xr_r[0] : q == 1 ? xr_r[1] : q == 2 ? xr_r[2] : xr_r[3]);
    if (mode == 0) {
        if (!u2) atomicAdd(ws + WS_A1 + base + lane, acc * x_l * 0.5f);
        else     atomicAdd(ws + WS_A2 + base + lane, acc * (xmax - x_l) * 0.5f * INV_ALPHA);

        // ---- folded k_pre: last block computes x/x2/max(x2) for step 2 ----
        __threadfence();
        __syncthreads();
        __shared__ bool last;
        if (tid == 0) {
            unsigned* cnt = (unsigned*)(ws + WS_CNT);
            last = (atomicAdd(cnt, 1u) == (unsigned)(gridDim.x - 1));
        }
        __syncthreads();
        if (last) {
            __threadfence();
            float vmax = -1e30f;
            for (int i = tid; i < BB; i += 256) {
                float a1 = __hip_atomic_load(ws + WS_A1 + i, __ATOMIC_RELAXED,
                                             __HIP_MEMORY_SCOPE_AGENT);
                float a2 = __hip_atomic_load(ws + WS_A2 + i, __ATOMIC_RELAXED,
                                             __HIP_MEMORY_SCOPE_AGENT);
                float m0 = xm[i];
                float xv  = oml * m0 + lam * a1;
                float x2v = oml * m0 + lam * a2;
                ws[WS_X + i]  = xv;
                ws[WS_X2 + i] = x2v;
                vmax = fmaxf(vmax, x2v);
            }
            #pragma unroll
            for (int off = 32; off > 0; off >>= 1)
                vmax = fmaxf(vmax, __shfl_xor(vmax, off, 64));
            __shared__ float rm[4];
            if (lane == 0) rm[wloc] = vmax;
            __syncthreads();
            if (tid == 0)
                ws[WS_XMX2] = fmaxf(fmaxf(rm[0], rm[1]), fmaxf(rm[2], rm[3]));
        }
    } else {
        if (!u2) atomicAdd(out + base + lane, acc * x_l * 0.5f);
        else     atomicAdd(out + 2 * BB + base + lane,
                           acc * (xmax - x_l) * 0.5f * INV_ALPHA);
    }
}

extern "C" void kernel_launch(void* const* d_in, const int* in_sizes, int n_in,
                              void* d_out, int out_size, void* d_ws, size_t ws_size,
                              hipStream_t stream) {
    const float* x_  = (const float*)d_in[0];
    const float* h_  = (const float*)d_in[1];
    const float* lw  = (const float*)d_in[2];
    const float* sp  = (const float*)d_in[3];
    const float* f1W0 = (const float*)d_in[4];   const float* f1b0 = (const float*)d_in[5];
    const float* f1W1 = (const float*)d_in[6];   const float* f1b1 = (const float*)d_in[7];
    const float* f1W2 = (const float*)d_in[8];   const float* f1b2 = (const float*)d_in[9];
    const float* f1W3 = (const float*)d_in[10];  const float* f1b3 = (const float*)d_in[11];
    const float* f1Wf = (const float*)d_in[12];
    const float* f2W0 = (const float*)d_in[13];  const float* f2b0 = (const float*)d_in[14];
    const float* f2W1 = (const float*)d_in[15];  const float* f2b1 = (const float*)d_in[16];
    const float* f2W2 = (const float*)d_in[17];  const float* f2b2 = (const float*)d_in[18];
    const float* f2W3 = (const float*)d_in[19];  const float* f2b3 = (const float*)d_in[20];
    const float* f2Wf = (const float*)d_in[21];
    float* out = (float*)d_out;
    float* ws  = (float*)d_ws;

    k_setup<<<337, 256, 0, stream>>>(x_, lw, sp,
                                     f1W0, f1W1, f1W2, f1W3,
                                     f2W0, f2W1, f2W2, f2W3, ws, out);
    k_int<<<512, 256, 0, stream>>>(0, ws, h_,
        f1b0, f1b1, f1b2, f1b3, f1Wf, f2b0, f2b1, f2b2, f2b3, f2Wf, out);
    k_int<<<512, 256, 0, stream>>>(1, ws, h_,
        f1b0, f1b1, f1b2, f1b3, f1Wf, f2b0, f2b1, f2b2, f2b3, f2Wf, out);
}

// Round 10
// 152.279 us; speedup vs baseline: 1.8345x; 1.0839x over previous
//
#include <hip/hip_runtime.h>
#include <math.h>

typedef _Float16 half8v __attribute__((ext_vector_type(8)));
typedef _Float16 half4v __attribute__((ext_vector_type(4)));
typedef _Float16 half2v __attribute__((ext_vector_type(2)));
typedef float float4v __attribute__((ext_vector_type(4)));

// ---- problem constants ----
#define BB    4096
#define INV_ALPHA (1.0f/0.9f)

// ---- workspace float offsets ----
#define WS_CCW  0
#define WS_CCS  64
#define WS_LAM  128
#define WS_PM16 160     // 16 block-maxes of x2_step1 (written by k_pre)
#define WS_PM   256     // 256 block-maxes of xm
#define WS_XM   512
#define WS_X    (WS_XM + BB)
#define WS_X2   (WS_X + BB)
#define WS_H    16384   // halfs region starts at byte 65536
// half offsets within WS_H
#define H_NET   8192
#define H_W2    4096
#define H_W0    16384   // + net*2048 : [64 j][32 k] zero-padded
#define H_W3    20480   // + net*64

#if defined(__has_builtin)
#if __has_builtin(__builtin_amdgcn_rcpf)
#define FRCP(x) __builtin_amdgcn_rcpf(x)
#endif
#if __has_builtin(__builtin_amdgcn_exp2f)
#define FEXP2(x) __builtin_amdgcn_exp2f(x)
#endif
#if __has_builtin(__builtin_amdgcn_logf)
#define FLOG2(x) __builtin_amdgcn_logf(x)
#endif
#endif
#ifndef FRCP
#define FRCP(x) (1.0f / (x))
#endif
#ifndef FEXP2
#define FEXP2(x) exp2f(x)
#endif
#ifndef FLOG2
#define FLOG2(x) log2f(x)
#endif

// act: 64 rows x 64 halfs, 16B column-blocks XOR-swizzled by row
__device__ __forceinline__ int swz(int row, int cb) {
    return (row << 6) + (((cb ^ (row & 7)) & 7) << 3);
}

// relu + pack f32x4 -> f16x4
__device__ __forceinline__ half4v pk_relu4(float4v c) {
#if defined(__has_builtin) && __has_builtin(__builtin_amdgcn_cvt_pkrtz)
    half2v a = __builtin_bit_cast(half2v,
        __builtin_amdgcn_cvt_pkrtz(fmaxf(c[0], 0.0f), fmaxf(c[1], 0.0f)));
    half2v b = __builtin_bit_cast(half2v,
        __builtin_amdgcn_cvt_pkrtz(fmaxf(c[2], 0.0f), fmaxf(c[3], 0.0f)));
    half4v o; o[0] = a[0]; o[1] = a[1]; o[2] = b[0]; o[3] = b[1];
    return o;
#else
    half4v o;
    o[0] = (_Float16)fmaxf(c[0], 0.0f); o[1] = (_Float16)fmaxf(c[1], 0.0f);
    o[2] = (_Float16)fmaxf(c[2], 0.0f); o[3] = (_Float16)fmaxf(c[3], 0.0f);
    return o;
#endif
}

// integrand tail: ELU+1 -> 5 powers -> 1/(f+1) dot Wf -> relu
__device__ __forceinline__ float tail5(float y,
        float p0, float p1, float p2, float p3, float p4,
        float wf0, float wf1, float wf2, float wf3, float wf4) {
    if (y <= 0.0f) y = FEXP2(y * 1.44269504f) - 1.0f;   // elu
    float z = y + 1.0f;
    float lg = FLOG2(z);
    float g = wf0 * FRCP(FEXP2(p0 * lg) + 1.0f)
            + wf1 * FRCP(FEXP2(p1 * lg) + 1.0f)
            + wf2 * FRCP(FEXP2(p2 * lg) + 1.0f)
            + wf3 * FRCP(FEXP2(p3 * lg) + 1.0f)
            + wf4 * FRCP(FEXP2(p4 * lg) + 1.0f);
    return fmaxf(g, 0.0f);
}

// ---- fused setup: xm + maxes | weight repack | CC + lam | zero accumulators ----
__global__ void k_setup(const float* __restrict__ x_, const float* __restrict__ lw,
                        const float* __restrict__ sp,
                        const float* __restrict__ f1W0, const float* __restrict__ f1W1,
                        const float* __restrict__ f1W2, const float* __restrict__ f1W3,
                        const float* __restrict__ f2W0, const float* __restrict__ f2W1,
                        const float* __restrict__ f2W2, const float* __restrict__ f2W3,
                        float* __restrict__ ws, float* __restrict__ out) {
    _Float16* wh = (_Float16*)(ws + WS_H);
    const int blk = blockIdx.x, tid = threadIdx.x;
    if (blk < 256) {
        int wave = tid >> 6, lane = tid & 63;
        float vmax = -1e30f;
        for (int r = 0; r < 4; ++r) {
            int row = blk * 16 + wave * 4 + r;
            float v = 0.0f;
            for (int i = lane; i < 100; i += 64) v = fmaf(x_[row * 100 + i], lw[i], v);
            #pragma unroll
            for (int off = 32; off > 0; off >>= 1) v += __shfl_xor(v, off, 64);
            if (lane == 0) ws[WS_XM + row] = v;
            vmax = fmaxf(vmax, v);
        }
        __shared__ float sm[4];
        if (lane == 0) sm[wave] = vmax;
        __syncthreads();
        if (tid == 0)
            ws[WS_PM + blk] = fmaxf(fmaxf(sm[0], sm[1]), fmaxf(sm[2], sm[3]));
    } else if (blk < 272) {
        int t = (blk - 256) * 256 + tid;       // 0..4095
        wh[t]                = (_Float16)f1W1[t];
        wh[H_W2 + t]         = (_Float16)f1W2[t];
        wh[H_NET + t]        = (_Float16)f2W1[t];
        wh[H_NET + H_W2 + t] = (_Float16)f2W2[t];
        if (t < 2048) {
            int j = t >> 5, k = t & 31;
            wh[H_W0 + t]        = (k < 5) ? (_Float16)f1W0[j * 5 + k] : (_Float16)0.0f;
            wh[H_W0 + 2048 + t] = (k < 5) ? (_Float16)f2W0[j * 5 + k] : (_Float16)0.0f;
        }
        if (t < 64) {
            wh[H_W3 + t]      = (_Float16)f1W3[t];
            wh[H_W3 + 64 + t] = (_Float16)f2W3[t];
        }
    } else if (blk == 272) {
        if (tid == 64) ws[WS_LAM] = 1.0f / (1.0f + expf(-sp[0]));
        if (tid <= 50) {
            int s = tid;
            ws[WS_CCS + s] = cospif((float)s / 50.0f);
            float acc = 0.0f;
            for (int a = 0; a <= 50; ++a) {
                float w;
                if (a == 0) w = 1.0f;
                else if ((a & 1) == 0) w = 2.0f / (1.0f - (float)(a * a));
                else continue;
                float l;
                if (s == 0) l = 0.5f;
                else {
                    int m = (a * s) % 100;
                    l = cospif((float)m / 50.0f);
                    if (s == 50) l *= 0.5f;
                }
                acc += l * 0.04f * w;
            }
            ws[WS_CCW + s] = acc;
        }
    } else {
        // zero accumulation targets: out[0..BB) and out[2BB..3BB)
        int t = (blk - 273) * 256 + tid;       // 0..8191
        out[t < BB ? t : BB + t] = 0.0f;
    }
}

// between steps: x/x2 for step1, 16 partial maxes of x2, re-zero accumulators
__global__ void k_pre(float* __restrict__ ws, float* __restrict__ out) {
    int b = blockIdx.x * 256 + threadIdx.x;
    float lam = ws[WS_LAM];
    float m = ws[WS_XM + b];
    float xv  = (1.0f - lam) * m + lam * out[b];
    float x2v = (1.0f - lam) * m + lam * out[2 * BB + b];
    ws[WS_X + b] = xv;
    ws[WS_X2 + b] = x2v;
    out[b] = 0.0f;
    out[2 * BB + b] = 0.0f;
    __shared__ float red[256];
    red[threadIdx.x] = x2v;
    __syncthreads();
    #pragma unroll
    for (int off = 128; off > 0; off >>= 1) {
        if (threadIdx.x < off)
            red[threadIdx.x] = fmaxf(red[threadIdx.x], red[threadIdx.x + off]);
        __syncthreads();
    }
    if (threadIdx.x == 0) ws[WS_PM16 + blockIdx.x] = red[0];
}

// Round-6 WIN structure + 24-waves-per-group, grid 768 = 3 blocks/CU
// co-resident. CRITICAL: keep __launch_bounds__(256,2) — the allocator's
// natural ~116 VGPR <= 170 (=512/3) and LDS 51200x3 <= 160 KB let the HW
// run 3 blocks/CU anyway; requesting 3 via launch bounds squeezes VGPRs
// to 84 and spills catastrophically (round-8 lesson).
// Block b (0..767): group g = b/6 (0..127), wave w = (b%6)*4+wloc (0..23).
// Group g owns items [(g&63)*64,+64) of net (g>=64 ? f2:f1). Wave w takes
// s = w, w+24 [, w+48 if w<3] -> covers s=0..50 exactly. The w==23 f1 wave
// in mode 1 computes out_first in its dead 3rd slot. One atomicAdd per
// item per wave. Weights in LDS fragment-major (spill-free).
__global__ __launch_bounds__(256, 2) void k_int(
    int mode, float* __restrict__ ws, const float* __restrict__ h_,
    const float* __restrict__ f1b0, const float* __restrict__ f1b1,
    const float* __restrict__ f1b2, const float* __restrict__ f1b3,
    const float* __restrict__ f1Wf,
    const float* __restrict__ f2b0, const float* __restrict__ f2b1,
    const float* __restrict__ f2b2, const float* __restrict__ f2b3,
    const float* __restrict__ f2Wf,
    float* __restrict__ out)
{
    __shared__ _Float16 act[4 * 64 * 64];   // 32 KB: per-wave slices
    __shared__ _Float16 w0f[4 * 16 * 8];    // 1 KB  : L0 frags (q==0 only)
    __shared__ _Float16 w1f[512 * 8];       // 8 KB  : L1 frags, frag-major
    __shared__ _Float16 w2f[512 * 8];       // 8 KB  : L2 frags, frag-major
    __shared__ float bl[192];               // biases: [layer*64 + feat]

    const int tid = threadIdx.x;
    const int blk = blockIdx.x;
    const int wloc = tid >> 6;
    const int lane = tid & 63;
    const int lo = lane & 15, q = lane >> 4;

    const int g = blk / 6;                    // 0..127
    const int w = (blk - g * 6) * 4 + wloc;   // 0..23
    const bool u2 = (g >= 64);
    const int base = (g & 63) << 6;
    const bool of_wave = (mode != 0) && (!u2) && (w == 23);

    const float* xm = ws + WS_XM;
    const float* xarr = ws + WS_X;
    const float* x2arr = ws + WS_X2;
    const _Float16* wh = (const _Float16*)(ws + WS_H);
    const float lam = ws[WS_LAM];
    const float oml = 1.0f - lam;

    const _Float16* W0h = wh + H_W0 + (u2 ? 2048 : 0);
    const _Float16* W1h = wh + (u2 ? H_NET : 0);
    const _Float16* W2h = W1h + H_W2;
    const _Float16* W3h = wh + H_W3 + (u2 ? 64 : 0);
    const float* B0 = u2 ? f2b0 : f1b0;
    const float* B1 = u2 ? f2b1 : f1b1;
    const float* B2 = u2 ? f2b2 : f1b2;
    const float* B3 = u2 ? f2b3 : f1b3;
    const float* WF = u2 ? f2Wf : f1Wf;
    const float p0 = u2 ? 1.5f : 1.1f;
    const float p1 = u2 ? 2.0f : 1.1f;
    const float p2 = u2 ? 2.5f : 1.5f;
    const float p3 = u2 ? 3.0f : 2.0f;
    const float p4 = u2 ? 3.5f : 2.5f;

    // ---- stage weights -> LDS, fragment-major (f = (m*2+kb)*64 + lane) ----
    #pragma unroll
    for (int f = tid; f < 512; f += 256) {
        int fm = f >> 7, fkb = (f >> 6) & 1, fl = f & 63;
        int flo = fl & 15, fq = fl >> 4;
        *(half8v*)(w1f + f * 8) =
            *(const half8v*)(W1h + (16 * fm + flo) * 64 + fkb * 32 + fq * 8);
        *(half8v*)(w2f + f * 8) =
            *(const half8v*)(W2h + (16 * fm + flo) * 64 + fkb * 32 + fq * 8);
    }
    if (tid < 64) {
        int fm = tid >> 4, flo = tid & 15;
        *(half8v*)(w0f + tid * 8) = *(const half8v*)(W0h + (16 * fm + flo) * 32);
    }
    if (tid < 192)
        bl[tid] = (tid < 64) ? B0[tid] : (tid < 128) ? B1[tid - 64] : B2[tid - 128];

    // ---- small per-lane pins (while staging is in flight) ----
    half4v w3r[4];
    #pragma unroll
    for (int m = 0; m < 4; ++m)
        w3r[m] = *(const half4v*)(W3h + 16 * m + 4 * q);
    const float B3s = B3[0];
    const float wf0 = WF[0], wf1 = WF[1], wf2 = WF[2], wf3 = WF[3], wf4 = WF[4];

    half8v zf;                            // zero fragment (shared)
    #pragma unroll
    for (int t2 = 0; t2 < 8; ++t2) zf[t2] = (_Float16)0.0f;

    float xr_r[4], x2_r[4];
    half8v tpl[4];                        // pre-packed B template (h in halfs)
    #pragma unroll
    for (int n = 0; n < 4; ++n) {
        int idx = base + 16 * n + lo;
        xr_r[n] = mode ? (u2 ? x2arr[idx] : xarr[idx]) : oml * xm[idx];
        float4 h4 = ((const float4*)h_)[idx];
        half8v e = zf;
        e[1] = (_Float16)h4.x; e[2] = (_Float16)h4.y;
        e[3] = (_Float16)h4.z; e[4] = (_Float16)h4.w;
        tpl[n] = (q == 0) ? e : zf;
        x2_r[n] = 0.0f;
    }
    if (of_wave) {
        #pragma unroll
        for (int n = 0; n < 4; ++n) x2_r[n] = x2arr[base + 16 * n + lo];
    }

    float xmax = 0.0f;
    if (u2) {
        if (mode) {
            float v = (lane < 16) ? ws[WS_PM16 + lane] : -1e30f;
            #pragma unroll
            for (int off = 32; off > 0; off >>= 1) v = fmaxf(v, __shfl_xor(v, off, 64));
            xmax = v + 10.0f;
        } else {
            const float* pm = ws + WS_PM;
            float v = fmaxf(fmaxf(pm[lane], pm[lane + 64]),
                            fmaxf(pm[lane + 128], pm[lane + 192]));
            #pragma unroll
            for (int off = 32; off > 0; off >>= 1) v = fmaxf(v, __shfl_xor(v, off, 64));
            xmax = oml * v + 10.0f;
        }
    }

    __syncthreads();                      // weights/biases staged

    _Float16* actw = act + (wloc << 12);  // private 4096-half slice
    const int np = (w < 3 || of_wave) ? 3 : 2;
    float acc = 0.0f;

    #pragma clang loop unroll(disable)
    for (int p = 0; p < np; ++p) {
        const bool of_iter = of_wave && (p == 2);
        float t = 0.0f, ccw_s = 0.0f;
        if (!of_iter) {
            int s = w + 24 * p;                     // <= 50 by construction
            t = (ws[WS_CCS + s] + 1.0f) * 0.5f;
            ccw_s = ws[WS_CCW + s];
        }

        // build B-operand for layer 0 from template (q==0 lanes carry k=0..4)
        half8v Bf0[4];
        #pragma unroll
        for (int n = 0; n < 4; ++n) {
            float xin;
            if (of_iter) xin = x2_r[n];
            else if (u2) xin = fmaf(t, xmax - xr_r[n], xr_r[n]);
            else         xin = xr_r[n] * t;
            half8v b = tpl[n];
            b[0] = (_Float16)((q == 0) ? xin : 0.0f);
            Bf0[n] = b;
        }

        // ---- layer 0: A-frag from LDS (broadcast reads, q==0 rows only) ----
        #pragma unroll
        for (int m = 0; m < 4; ++m) {
            half8v a0 = (q == 0) ? *(const half8v*)(w0f + (m * 16 + lo) * 8) : zf;
            float4v b0 = *(const float4v*)(bl + 16 * m + 4 * q);
            #pragma unroll
            for (int n = 0; n < 4; ++n) {
                float4v c = __builtin_amdgcn_mfma_f32_16x16x32_f16(a0, Bf0[n], b0, 0, 0, 0);
                *(half4v*)(actw + swz(16 * n + lo, 2 * m + (q >> 1)) + 4 * (q & 1)) = pk_relu4(c);
            }
        }

        // ---- layer 1: A-frags lane-consecutive from LDS ----
        {
            half8v Bf[2][4];
            #pragma unroll
            for (int kb = 0; kb < 2; ++kb)
                #pragma unroll
                for (int n = 0; n < 4; ++n)
                    Bf[kb][n] = *(const half8v*)(actw + swz(16 * n + lo, 4 * kb + q));
            #pragma unroll
            for (int m = 0; m < 4; ++m) {
                half8v a10 = *(const half8v*)(w1f + ((m * 2 + 0) * 64 + lane) * 8);
                half8v a11 = *(const half8v*)(w1f + ((m * 2 + 1) * 64 + lane) * 8);
                float4v b1 = *(const float4v*)(bl + 64 + 16 * m + 4 * q);
                #pragma unroll
                for (int n = 0; n < 4; ++n) {
                    float4v c = __builtin_amdgcn_mfma_f32_16x16x32_f16(a10, Bf[0][n], b1, 0, 0, 0);
                    c = __builtin_amdgcn_mfma_f32_16x16x32_f16(a11, Bf[1][n], c, 0, 0, 0);
                    *(half4v*)(actw + swz(16 * n + lo, 2 * m + (q >> 1)) + 4 * (q & 1)) = pk_relu4(c);
                }
            }
        }

        // ---- layer 2 with fused W3-dot ----
        float part[4] = {0.0f, 0.0f, 0.0f, 0.0f};
        {
            half8v Bf[2][4];
            #pragma unroll
            for (int kb = 0; kb < 2; ++kb)
                #pragma unroll
                for (int n = 0; n < 4; ++n)
                    Bf[kb][n] = *(const half8v*)(actw + swz(16 * n + lo, 4 * kb + q));
            #pragma unroll
            for (int m = 0; m < 4; ++m) {
                half8v a20 = *(const half8v*)(w2f + ((m * 2 + 0) * 64 + lane) * 8);
                half8v a21 = *(const half8v*)(w2f + ((m * 2 + 1) * 64 + lane) * 8);
                float4v b2 = *(const float4v*)(bl + 128 + 16 * m + 4 * q);
                #pragma unroll
                for (int n = 0; n < 4; ++n) {
                    float4v c = __builtin_amdgcn_mfma_f32_16x16x32_f16(a20, Bf[0][n], b2, 0, 0, 0);
                    c = __builtin_amdgcn_mfma_f32_16x16x32_f16(a21, Bf[1][n], c, 0, 0, 0);
                    #pragma unroll
                    for (int e = 0; e < 4; ++e)
                        part[n] = fmaf((float)w3r[m][e], fmaxf(c[e], 0.0f), part[n]);
                }
            }
        }

        // complete each row's dot across quads; lane keeps its own row (=lane)
        #pragma unroll
        for (int n = 0; n < 4; ++n) {
            part[n] += __shfl_xor(part[n], 16, 64);
            part[n] += __shfl_xor(part[n], 32, 64);
        }
        float y = B3s + (q == 0 ? part[0] : q == 1 ? part[1] : q == 2 ? part[2] : part[3]);

        float val = tail5(y, p0, p1, p2, p3, p4, wf0, wf1, wf2, wf3, wf4);

        if (of_iter) out[BB + base + lane] = val;
        else         acc = fmaf(ccw_s, val, acc);
    }

    // ---- per-item epilogue: lane owns item base+lane (row 16q+lo == lane) ----
    const float x_l = (q == 0 ? xr_r[0] : q == 1 ? xr_r[1] : q == 2 ? xr_r[2] : xr_r[3]);
    if (!u2) {
        atomicAdd(out + base + lane, acc * x_l * 0.5f);
    } else {
        atomicAdd(out + 2 * BB + base + lane, acc * (xmax - x_l) * 0.5f * INV_ALPHA);
    }
}

extern "C" void kernel_launch(void* const* d_in, const int* in_sizes, int n_in,
                              void* d_out, int out_size, void* d_ws, size_t ws_size,
                              hipStream_t stream) {
    const float* x_  = (const float*)d_in[0];
    const float* h_  = (const float*)d_in[1];
    const float* lw  = (const float*)d_in[2];
    const float* sp  = (const float*)d_in[3];
    const float* f1W0 = (const float*)d_in[4];   const float* f1b0 = (const float*)d_in[5];
    const float* f1W1 = (const float*)d_in[6];   const float* f1b1 = (const float*)d_in[7];
    const float* f1W2 = (const float*)d_in[8];   const float* f1b2 = (const float*)d_in[9];
    const float* f1W3 = (const float*)d_in[10];  const float* f1b3 = (const float*)d_in[11];
    const float* f1Wf = (const float*)d_in[12];
    const float* f2W0 = (const float*)d_in[13];  const float* f2b0 = (const float*)d_in[14];
    const float* f2W1 = (const float*)d_in[15];  const float* f2b1 = (const float*)d_in[16];
    const float* f2W2 = (const float*)d_in[17];  const float* f2b2 = (const float*)d_in[18];
    const float* f2W3 = (const float*)d_in[19];  const float* f2b3 = (const float*)d_in[20];
    const float* f2Wf = (const float*)d_in[21];
    float* out = (float*)d_out;
    float* ws  = (float*)d_ws;

    k_setup<<<305, 256, 0, stream>>>(x_, lw, sp,
                                     f1W0, f1W1, f1W2, f1W3,
                                     f2W0, f2W1, f2W2, f2W3, ws, out);
    k_int<<<768, 256, 0, stream>>>(0, ws, h_,
        f1b0, f1b1, f1b2, f1b3, f1Wf, f2b0, f2b1, f2b2, f2b3, f2Wf, out);
    k_pre<<<16, 256, 0, stream>>>(ws, out);
    k_int<<<768, 256, 0, stream>>>(1, ws, h_,
        f1b0, f1b1, f1b2, f1b3, f1Wf, f2b0, f2b1, f2b2, f2b3, f2Wf, out);
}

// Round 11
// 142.379 us; speedup vs baseline: 1.9621x; 1.0695x over previous
//
#include <hip/hip_runtime.h>
#include <math.h>

typedef _Float16 half8v __attribute__((ext_vector_type(8)));
typedef _Float16 half4v __attribute__((ext_vector_type(4)));
typedef _Float16 half2v __attribute__((ext_vector_type(2)));
typedef float float4v __attribute__((ext_vector_type(4)));

// ---- problem constants ----
#define BB    4096
#define INV_ALPHA (1.0f/0.9f)

// ---- workspace float offsets ----
#define WS_CCW  0
#define WS_CCS  64
#define WS_LAM  128
#define WS_PM16 160     // 16 block-maxes of x2_step1 (written by k_pre)
#define WS_PM   256     // 256 block-maxes of xm
#define WS_XM   512
#define WS_X    (WS_XM + BB)
#define WS_X2   (WS_X + BB)
#define WS_H    16384   // halfs region starts at byte 65536
// half offsets within WS_H:
//   0     : W1 frag-major f1 (4096) | 4096 : W1 frag-major f2
//   8192  : W2 frag-major f1        | 12288: W2 frag-major f2
//   16384 : W0 zero-padded [64 j][32 k] (f1, then f2 at +2048)
//   20480 : W3 (f1 64, f2 64)
#define H_W0    16384
#define H_W3    20480

#if defined(__has_builtin)
#if __has_builtin(__builtin_amdgcn_rcpf)
#define FRCP(x) __builtin_amdgcn_rcpf(x)
#endif
#if __has_builtin(__builtin_amdgcn_exp2f)
#define FEXP2(x) __builtin_amdgcn_exp2f(x)
#endif
#if __has_builtin(__builtin_amdgcn_logf)
#define FLOG2(x) __builtin_amdgcn_logf(x)
#endif
#endif
#ifndef FRCP
#define FRCP(x) (1.0f / (x))
#endif
#ifndef FEXP2
#define FEXP2(x) exp2f(x)
#endif
#ifndef FLOG2
#define FLOG2(x) log2f(x)
#endif

// act: 64 rows x 64 halfs, 16B column-blocks XOR-swizzled by row
__device__ __forceinline__ int swz(int row, int cb) {
    return (row << 6) + (((cb ^ (row & 7)) & 7) << 3);
}

// relu + pack f32x4 -> f16x4
__device__ __forceinline__ half4v pk_relu4(float4v c) {
#if defined(__has_builtin) && __has_builtin(__builtin_amdgcn_cvt_pkrtz)
    half2v a = __builtin_bit_cast(half2v,
        __builtin_amdgcn_cvt_pkrtz(fmaxf(c[0], 0.0f), fmaxf(c[1], 0.0f)));
    half2v b = __builtin_bit_cast(half2v,
        __builtin_amdgcn_cvt_pkrtz(fmaxf(c[2], 0.0f), fmaxf(c[3], 0.0f)));
    half4v o; o[0] = a[0]; o[1] = a[1]; o[2] = b[0]; o[3] = b[1];
    return o;
#else
    half4v o;
    o[0] = (_Float16)fmaxf(c[0], 0.0f); o[1] = (_Float16)fmaxf(c[1], 0.0f);
    o[2] = (_Float16)fmaxf(c[2], 0.0f); o[3] = (_Float16)fmaxf(c[3], 0.0f);
    return o;
#endif
}

// integrand tail: ELU+1 -> 5 powers -> 1/(f+1) dot Wf -> relu
__device__ __forceinline__ float tail5(float y,
        float p0, float p1, float p2, float p3, float p4,
        float wf0, float wf1, float wf2, float wf3, float wf4) {
    if (y <= 0.0f) y = FEXP2(y * 1.44269504f) - 1.0f;   // elu
    float z = y + 1.0f;
    float lg = FLOG2(z);
    float g = wf0 * FRCP(FEXP2(p0 * lg) + 1.0f)
            + wf1 * FRCP(FEXP2(p1 * lg) + 1.0f)
            + wf2 * FRCP(FEXP2(p2 * lg) + 1.0f)
            + wf3 * FRCP(FEXP2(p3 * lg) + 1.0f)
            + wf4 * FRCP(FEXP2(p4 * lg) + 1.0f);
    return fmaxf(g, 0.0f);
}

// ---- fused setup: xm + maxes | weight repack (FRAG-MAJOR) | CC + lam | zero ----
__global__ void k_setup(const float* __restrict__ x_, const float* __restrict__ lw,
                        const float* __restrict__ sp,
                        const float* __restrict__ f1W0, const float* __restrict__ f1W1,
                        const float* __restrict__ f1W2, const float* __restrict__ f1W3,
                        const float* __restrict__ f2W0, const float* __restrict__ f2W1,
                        const float* __restrict__ f2W2, const float* __restrict__ f2W3,
                        float* __restrict__ ws, float* __restrict__ out) {
    _Float16* wh = (_Float16*)(ws + WS_H);
    const int blk = blockIdx.x, tid = threadIdx.x;
    if (blk < 256) {
        int wave = tid >> 6, lane = tid & 63;
        float vmax = -1e30f;
        for (int r = 0; r < 4; ++r) {
            int row = blk * 16 + wave * 4 + r;
            float v = 0.0f;
            for (int i = lane; i < 100; i += 64) v = fmaf(x_[row * 100 + i], lw[i], v);
            #pragma unroll
            for (int off = 32; off > 0; off >>= 1) v += __shfl_xor(v, off, 64);
            if (lane == 0) ws[WS_XM + row] = v;
            vmax = fmaxf(vmax, v);
        }
        __shared__ float sm[4];
        if (lane == 0) sm[wave] = vmax;
        __syncthreads();
        if (tid == 0)
            ws[WS_PM + blk] = fmaxf(fmaxf(sm[0], sm[1]), fmaxf(sm[2], sm[3]));
    } else if (blk < 272) {
        int t = (blk - 256) * 256 + tid;       // 0..4095 over [64 j][64 k]
        // fragment-major position: frag f = (m*2+kb)*64 + (q*16+lo), elem e
        int j = t >> 6, k = t & 63;
        int fm = j >> 4, flo = j & 15;
        int fkb = k >> 5, kc = k & 31, fq = kc >> 3, fe = kc & 7;
        int fragpos = (((fm * 2 + fkb) * 64 + fq * 16 + flo) << 3) + fe;
        wh[fragpos]         = (_Float16)f1W1[t];
        wh[4096 + fragpos]  = (_Float16)f2W1[t];
        wh[8192 + fragpos]  = (_Float16)f1W2[t];
        wh[12288 + fragpos] = (_Float16)f2W2[t];
        if (t < 2048) {
            int j0 = t >> 5, k0 = t & 31;
            wh[H_W0 + t]        = (k0 < 5) ? (_Float16)f1W0[j0 * 5 + k0] : (_Float16)0.0f;
            wh[H_W0 + 2048 + t] = (k0 < 5) ? (_Float16)f2W0[j0 * 5 + k0] : (_Float16)0.0f;
        }
        if (t < 64) {
            wh[H_W3 + t]      = (_Float16)f1W3[t];
            wh[H_W3 + 64 + t] = (_Float16)f2W3[t];
        }
    } else if (blk == 272) {
        if (tid == 64) ws[WS_LAM] = 1.0f / (1.0f + expf(-sp[0]));
        if (tid <= 50) {
            int s = tid;
            ws[WS_CCS + s] = cospif((float)s / 50.0f);
            float acc = 0.0f;
            for (int a = 0; a <= 50; ++a) {
                float w;
                if (a == 0) w = 1.0f;
                else if ((a & 1) == 0) w = 2.0f / (1.0f - (float)(a * a));
                else continue;
                float l;
                if (s == 0) l = 0.5f;
                else {
                    int m = (a * s) % 100;
                    l = cospif((float)m / 50.0f);
                    if (s == 50) l *= 0.5f;
                }
                acc += l * 0.04f * w;
            }
            ws[WS_CCW + s] = acc;
        }
    } else {
        // zero accumulation targets: out[0..BB) and out[2BB..3BB)
        int t = (blk - 273) * 256 + tid;       // 0..8191
        out[t < BB ? t : BB + t] = 0.0f;
    }
}

// between steps: x/x2 for step1, 16 partial maxes of x2, re-zero accumulators
__global__ void k_pre(float* __restrict__ ws, float* __restrict__ out) {
    int b = blockIdx.x * 256 + threadIdx.x;
    float lam = ws[WS_LAM];
    float m = ws[WS_XM + b];
    float xv  = (1.0f - lam) * m + lam * out[b];
    float x2v = (1.0f - lam) * m + lam * out[2 * BB + b];
    ws[WS_X + b] = xv;
    ws[WS_X2 + b] = x2v;
    out[b] = 0.0f;
    out[2 * BB + b] = 0.0f;
    __shared__ float red[256];
    red[threadIdx.x] = x2v;
    __syncthreads();
    #pragma unroll
    for (int off = 128; off > 0; off >>= 1) {
        if (threadIdx.x < off)
            red[threadIdx.x] = fmaxf(red[threadIdx.x], red[threadIdx.x + off]);
        __syncthreads();
    }
    if (threadIdx.x == 0) ws[WS_PM16 + blockIdx.x] = red[0];
}

// L2-direct weights variant. L1/L2 A-fragments are NOT staged in LDS: they
// are read per pass straight from ws (frag-major, lane-consecutive 16B ->
// coalesced, permanently L2-resident at 32 KB total). This cuts LDS/block
// 50->34 KB (=> 4 blocks/CU resident) and shrinks the per-block prologue
// ~3x, which rounds 7/10 showed was the cost of more blocks. Grid 1024 =
// 4 blocks/CU x 256 CU fully co-resident, 32 waves/group, np<=2.
// CRITICAL: __launch_bounds__(256,2) — natural VGPR ~116 <= 128 allows 4
// waves/SIMD; requesting more via launch bounds squeezes to 84 and spills
// (round-8 lesson). Block b (0..1023): group g = b>>3 (0..127), wave
// w = (b&7)*4+wloc (0..31). Group g owns items [(g&63)*64,+64) of net
// (g>=64 ? f2:f1). Wave w: s = w, and s = w+32 iff w<=18 (covers 0..50).
// The w==31 f1 wave in mode 1 computes out_first in its dead 2nd slot.
__global__ __launch_bounds__(256, 2) void k_int(
    int mode, float* __restrict__ ws, const float* __restrict__ h_,
    const float* __restrict__ f1b0, const float* __restrict__ f1b1,
    const float* __restrict__ f1b2, const float* __restrict__ f1b3,
    const float* __restrict__ f1Wf,
    const float* __restrict__ f2b0, const float* __restrict__ f2b1,
    const float* __restrict__ f2b2, const float* __restrict__ f2b3,
    const float* __restrict__ f2Wf,
    float* __restrict__ out)
{
    __shared__ _Float16 act[4 * 64 * 64];   // 32 KB: per-wave slices
    __shared__ _Float16 w0f[4 * 16 * 8];    // 1 KB  : L0 frags (q==0 only)
    __shared__ float bl[192];               // biases: [layer*64 + feat]

    const int tid = threadIdx.x;
    const int blk = blockIdx.x;
    const int wloc = tid >> 6;
    const int lane = tid & 63;
    const int lo = lane & 15, q = lane >> 4;

    const int g = blk >> 3;               // 0..127
    const int w = (blk & 7) * 4 + wloc;   // 0..31
    const bool u2 = (g >= 64);
    const int base = (g & 63) << 6;
    const bool of_wave = (mode != 0) && (!u2) && (w == 31);

    const float* xm = ws + WS_XM;
    const float* xarr = ws + WS_X;
    const float* x2arr = ws + WS_X2;
    const _Float16* wh = (const _Float16*)(ws + WS_H);
    const float lam = ws[WS_LAM];
    const float oml = 1.0f - lam;

    const _Float16* W1F = wh + (u2 ? 4096 : 0);          // frag-major L1
    const _Float16* W2F = wh + 8192 + (u2 ? 4096 : 0);   // frag-major L2
    const _Float16* W0h = wh + H_W0 + (u2 ? 2048 : 0);
    const _Float16* W3h = wh + H_W3 + (u2 ? 64 : 0);
    const float* B0 = u2 ? f2b0 : f1b0;
    const float* B1 = u2 ? f2b1 : f1b1;
    const float* B2 = u2 ? f2b2 : f1b2;
    const float* B3 = u2 ? f2b3 : f1b3;
    const float* WF = u2 ? f2Wf : f1Wf;
    const float p0 = u2 ? 1.5f : 1.1f;
    const float p1 = u2 ? 2.0f : 1.1f;
    const float p2 = u2 ? 2.5f : 1.5f;
    const float p3 = u2 ? 3.0f : 2.0f;
    const float p4 = u2 ? 3.5f : 2.5f;

    // ---- tiny LDS staging: L0 frags + biases only ----
    if (tid < 64) {
        int fm = tid >> 4, flo = tid & 15;
        *(half8v*)(w0f + tid * 8) = *(const half8v*)(W0h + (16 * fm + flo) * 32);
    }
    if (tid < 192)
        bl[tid] = (tid < 64) ? B0[tid] : (tid < 128) ? B1[tid - 64] : B2[tid - 128];

    // ---- small per-lane pins ----
    half4v w3r[4];
    #pragma unroll
    for (int m = 0; m < 4; ++m)
        w3r[m] = *(const half4v*)(W3h + 16 * m + 4 * q);
    const float B3s = B3[0];
    const float wf0 = WF[0], wf1 = WF[1], wf2 = WF[2], wf3 = WF[3], wf4 = WF[4];

    half8v zf;                            // zero fragment (shared)
    #pragma unroll
    for (int t2 = 0; t2 < 8; ++t2) zf[t2] = (_Float16)0.0f;

    float xr_r[4], x2_r[4];
    half8v tpl[4];                        // pre-packed B template (h in halfs)
    #pragma unroll
    for (int n = 0; n < 4; ++n) {
        int idx = base + 16 * n + lo;
        xr_r[n] = mode ? (u2 ? x2arr[idx] : xarr[idx]) : oml * xm[idx];
        float4 h4 = ((const float4*)h_)[idx];
        half8v e = zf;
        e[1] = (_Float16)h4.x; e[2] = (_Float16)h4.y;
        e[3] = (_Float16)h4.z; e[4] = (_Float16)h4.w;
        tpl[n] = (q == 0) ? e : zf;
        x2_r[n] = 0.0f;
    }
    if (of_wave) {
        #pragma unroll
        for (int n = 0; n < 4; ++n) x2_r[n] = x2arr[base + 16 * n + lo];
    }

    float xmax = 0.0f;
    if (u2) {
        if (mode) {
            float v = (lane < 16) ? ws[WS_PM16 + lane] : -1e30f;
            #pragma unroll
            for (int off = 32; off > 0; off >>= 1) v = fmaxf(v, __shfl_xor(v, off, 64));
            xmax = v + 10.0f;
        } else {
            const float* pm = ws + WS_PM;
            float v = fmaxf(fmaxf(pm[lane], pm[lane + 64]),
                            fmaxf(pm[lane + 128], pm[lane + 192]));
            #pragma unroll
            for (int off = 32; off > 0; off >>= 1) v = fmaxf(v, __shfl_xor(v, off, 64));
            xmax = oml * v + 10.0f;
        }
    }

    __syncthreads();                      // w0f/biases staged

    _Float16* actw = act + (wloc << 12);  // private 4096-half slice
    const int np = (w <= 18 || of_wave) ? 2 : 1;
    float acc = 0.0f;

    #pragma clang loop unroll(disable)
    for (int p = 0; p < np; ++p) {
        const bool of_iter = of_wave && (p == 1);
        float t = 0.0f, ccw_s = 0.0f;
        if (!of_iter) {
            int s = w + 32 * p;                     // <= 50 by construction
            t = (ws[WS_CCS + s] + 1.0f) * 0.5f;
            ccw_s = ws[WS_CCW + s];
        }

        // build B-operand for layer 0 from template (q==0 lanes carry k=0..4)
        half8v Bf0[4];
        #pragma unroll
        for (int n = 0; n < 4; ++n) {
            float xin;
            if (of_iter) xin = x2_r[n];
            else if (u2) xin = fmaf(t, xmax - xr_r[n], xr_r[n]);
            else         xin = xr_r[n] * t;
            half8v b = tpl[n];
            b[0] = (_Float16)((q == 0) ? xin : 0.0f);
            Bf0[n] = b;
        }

        // ---- layer 0: A-frag from LDS (broadcast reads, q==0 rows only) ----
        #pragma unroll
        for (int m = 0; m < 4; ++m) {
            half8v a0 = (q == 0) ? *(const half8v*)(w0f + (m * 16 + lo) * 8) : zf;
            float4v b0 = *(const float4v*)(bl + 16 * m + 4 * q);
            #pragma unroll
            for (int n = 0; n < 4; ++n) {
                float4v c = __builtin_amdgcn_mfma_f32_16x16x32_f16(a0, Bf0[n], b0, 0, 0, 0);
                *(half4v*)(actw + swz(16 * n + lo, 2 * m + (q >> 1)) + 4 * (q & 1)) = pk_relu4(c);
            }
        }

        // ---- layer 1: A-frags direct from L2 (frag-major, coalesced) ----
        {
            half8v Bf[2][4];
            #pragma unroll
            for (int kb = 0; kb < 2; ++kb)
                #pragma unroll
                for (int n = 0; n < 4; ++n)
                    Bf[kb][n] = *(const half8v*)(actw + swz(16 * n + lo, 4 * kb + q));
            #pragma unroll
            for (int m = 0; m < 4; ++m) {
                half8v a10 = *(const half8v*)(W1F + ((2 * m + 0) * 64 + lane) * 8);
                half8v a11 = *(const half8v*)(W1F + ((2 * m + 1) * 64 + lane) * 8);
                float4v b1 = *(const float4v*)(bl + 64 + 16 * m + 4 * q);
                #pragma unroll
                for (int n = 0; n < 4; ++n) {
                    float4v c = __builtin_amdgcn_mfma_f32_16x16x32_f16(a10, Bf[0][n], b1, 0, 0, 0);
                    c = __builtin_amdgcn_mfma_f32_16x16x32_f16(a11, Bf[1][n], c, 0, 0, 0);
                    *(half4v*)(actw + swz(16 * n + lo, 2 * m + (q >> 1)) + 4 * (q & 1)) = pk_relu4(c);
                }
            }
        }

        // ---- layer 2 with fused W3-dot: A-frags direct from L2 ----
        float part[4] = {0.0f, 0.0f, 0.0f, 0.0f};
        {
            half8v Bf[2][4];
            #pragma unroll
            for (int kb = 0; kb < 2; ++kb)
                #pragma unroll
                for (int n = 0; n < 4; ++n)
                    Bf[kb][n] = *(const half8v*)(actw + swz(16 * n + lo, 4 * kb + q));
            #pragma unroll
            for (int m = 0; m < 4; ++m) {
                half8v a20 = *(const half8v*)(W2F + ((2 * m + 0) * 64 + lane) * 8);
                half8v a21 = *(const half8v*)(W2F + ((2 * m + 1) * 64 + lane) * 8);
                float4v b2 = *(const float4v*)(bl + 128 + 16 * m + 4 * q);
                #pragma unroll
                for (int n = 0; n < 4; ++n) {
                    float4v c = __builtin_amdgcn_mfma_f32_16x16x32_f16(a20, Bf[0][n], b2, 0, 0, 0);
                    c = __builtin_amdgcn_mfma_f32_16x16x32_f16(a21, Bf[1][n], c, 0, 0, 0);
                    #pragma unroll
                    for (int e = 0; e < 4; ++e)
                        part[n] = fmaf((float)w3r[m][e], fmaxf(c[e], 0.0f), part[n]);
                }
            }
        }

        // complete each row's dot across quads; lane keeps its own row (=lane)
        #pragma unroll
        for (int n = 0; n < 4; ++n) {
            part[n] += __shfl_xor(part[n], 16, 64);
            part[n] += __shfl_xor(part[n], 32, 64);
        }
        float y = B3s + (q == 0 ? part[0] : q == 1 ? part[1] : q == 2 ? part[2] : part[3]);

        float val = tail5(y, p0, p1, p2, p3, p4, wf0, wf1, wf2, wf3, wf4);

        if (of_iter) out[BB + base + lane] = val;
        else         acc = fmaf(ccw_s, val, acc);
    }

    // ---- per-item epilogue: lane owns item base+lane (row 16q+lo == lane) ----
    const float x_l = (q == 0 ? xr_r[0] : q == 1 ? xr_r[1] : q == 2 ? xr_r[2] : xr_r[3]);
    if (!u2) {
        atomicAdd(out + base + lane, acc * x_l * 0.5f);
    } else {
        atomicAdd(out + 2 * BB + base + lane, acc * (xmax - x_l) * 0.5f * INV_ALPHA);
    }
}

extern "C" void kernel_launch(void* const* d_in, const int* in_sizes, int n_in,
                              void* d_out, int out_size, void* d_ws, size_t ws_size,
                              hipStream_t stream) {
    const float* x_  = (const float*)d_in[0];
    const float* h_  = (const float*)d_in[1];
    const float* lw  = (const float*)d_in[2];
    const float* sp  = (const float*)d_in[3];
    const float* f1W0 = (const float*)d_in[4];   const float* f1b0 = (const float*)d_in[5];
    const float* f1W1 = (const float*)d_in[6];   const float* f1b1 = (const float*)d_in[7];
    const float* f1W2 = (const float*)d_in[8];   const float* f1b2 = (const float*)d_in[9];
    const float* f1W3 = (const float*)d_in[10];  const float* f1b3 = (const float*)d_in[11];
    const float* f1Wf = (const float*)d_in[12];
    const float* f2W0 = (const float*)d_in[13];  const float* f2b0 = (const float*)d_in[14];
    const float* f2W1 = (const float*)d_in[15];  const float* f2b1 = (const float*)d_in[16];
    const float* f2W2 = (const float*)d_in[17];  const float* f2b2 = (const float*)d_in[18];
    const float* f2W3 = (const float*)d_in[19];  const float* f2b3 = (const float*)d_in[20];
    const float* f2Wf = (const float*)d_in[21];
    float* out = (float*)d_out;
    float* ws  = (float*)d_ws;

    k_setup<<<305, 256, 0, stream>>>(x_, lw, sp,
                                     f1W0, f1W1, f1W2, f1W3,
                                     f2W0, f2W1, f2W2, f2W3, ws, out);
    k_int<<<1024, 256, 0, stream>>>(0, ws, h_,
        f1b0, f1b1, f1b2, f1b3, f1Wf, f2b0, f2b1, f2b2, f2b3, f2Wf, out);
    k_pre<<<16, 256, 0, stream>>>(ws, out);
    k_int<<<1024, 256, 0, stream>>>(1, ws, h_,
        f1b0, f1b1, f1b2, f1b3, f1Wf, f2b0, f2b1, f2b2, f2b3, f2Wf, out);
}

// Round 12
// 136.558 us; speedup vs baseline: 2.0457x; 1.0426x over previous
//
#include <hip/hip_runtime.h>
#include <math.h>

typedef _Float16 half8v __attribute__((ext_vector_type(8)));
typedef _Float16 half4v __attribute__((ext_vector_type(4)));
typedef _Float16 half2v __attribute__((ext_vector_type(2)));
typedef float float4v __attribute__((ext_vector_type(4)));

// ---- problem constants ----
#define BB    4096
#define INV_ALPHA (1.0f/0.9f)

// ---- workspace float offsets ----
#define WS_CCW  0
#define WS_CCS  64
#define WS_LAM  128
#define WS_PM   256          // 256 block-maxes of xm (for mode-0 u2 xmax)
#define WS_XM   512          // 4096
#define WS_A1   4608         // step-1 I1 accumulators (4096)
#define WS_A2   8704         // step-1 I2 accumulators (4096, ends 12800)
#define WS_H    16384        // halfs region starts at byte 65536
// half offsets within WS_H (round-6 layout)
#define H_NET   8192
#define H_W2    4096
#define H_W0    16384   // + net*2048 : [64 j][32 k] zero-padded
#define H_W3    20480   // + net*64

#if defined(__has_builtin)
#if __has_builtin(__builtin_amdgcn_rcpf)
#define FRCP(x) __builtin_amdgcn_rcpf(x)
#endif
#if __has_builtin(__builtin_amdgcn_exp2f)
#define FEXP2(x) __builtin_amdgcn_exp2f(x)
#endif
#if __has_builtin(__builtin_amdgcn_logf)
#define FLOG2(x) __builtin_amdgcn_logf(x)
#endif
#endif
#ifndef FRCP
#define FRCP(x) (1.0f / (x))
#endif
#ifndef FEXP2
#define FEXP2(x) exp2f(x)
#endif
#ifndef FLOG2
#define FLOG2(x) log2f(x)
#endif

// act: 64 rows x 64 halfs, 16B column-blocks XOR-swizzled by row
__device__ __forceinline__ int swz(int row, int cb) {
    return (row << 6) + (((cb ^ (row & 7)) & 7) << 3);
}

// relu + pack f32x4 -> f16x4
__device__ __forceinline__ half4v pk_relu4(float4v c) {
#if defined(__has_builtin) && __has_builtin(__builtin_amdgcn_cvt_pkrtz)
    half2v a = __builtin_bit_cast(half2v,
        __builtin_amdgcn_cvt_pkrtz(fmaxf(c[0], 0.0f), fmaxf(c[1], 0.0f)));
    half2v b = __builtin_bit_cast(half2v,
        __builtin_amdgcn_cvt_pkrtz(fmaxf(c[2], 0.0f), fmaxf(c[3], 0.0f)));
    half4v o; o[0] = a[0]; o[1] = a[1]; o[2] = b[0]; o[3] = b[1];
    return o;
#else
    half4v o;
    o[0] = (_Float16)fmaxf(c[0], 0.0f); o[1] = (_Float16)fmaxf(c[1], 0.0f);
    o[2] = (_Float16)fmaxf(c[2], 0.0f); o[3] = (_Float16)fmaxf(c[3], 0.0f);
    return o;
#endif
}

// integrand tail: ELU+1 -> 5 powers -> 1/(f+1) dot Wf -> relu
__device__ __forceinline__ float tail5(float y,
        float p0, float p1, float p2, float p3, float p4,
        float wf0, float wf1, float wf2, float wf3, float wf4) {
    if (y <= 0.0f) y = FEXP2(y * 1.44269504f) - 1.0f;   // elu
    float z = y + 1.0f;
    float lg = FLOG2(z);
    float g = wf0 * FRCP(FEXP2(p0 * lg) + 1.0f)
            + wf1 * FRCP(FEXP2(p1 * lg) + 1.0f)
            + wf2 * FRCP(FEXP2(p2 * lg) + 1.0f)
            + wf3 * FRCP(FEXP2(p3 * lg) + 1.0f)
            + wf4 * FRCP(FEXP2(p4 * lg) + 1.0f);
    return fmaxf(g, 0.0f);
}

// ---- fused setup: xm + maxes | weight repack | CC + lam | zero A1/A2 + out ----
__global__ void k_setup(const float* __restrict__ x_, const float* __restrict__ lw,
                        const float* __restrict__ sp,
                        const float* __restrict__ f1W0, const float* __restrict__ f1W1,
                        const float* __restrict__ f1W2, const float* __restrict__ f1W3,
                        const float* __restrict__ f2W0, const float* __restrict__ f2W1,
                        const float* __restrict__ f2W2, const float* __restrict__ f2W3,
                        float* __restrict__ ws, float* __restrict__ out) {
    _Float16* wh = (_Float16*)(ws + WS_H);
    const int blk = blockIdx.x, tid = threadIdx.x;
    if (blk < 256) {
        int wave = tid >> 6, lane = tid & 63;
        float vmax = -1e30f;
        for (int r = 0; r < 4; ++r) {
            int row = blk * 16 + wave * 4 + r;
            float v = 0.0f;
            for (int i = lane; i < 100; i += 64) v = fmaf(x_[row * 100 + i], lw[i], v);
            #pragma unroll
            for (int off = 32; off > 0; off >>= 1) v += __shfl_xor(v, off, 64);
            if (lane == 0) ws[WS_XM + row] = v;
            vmax = fmaxf(vmax, v);
        }
        __shared__ float sm[4];
        if (lane == 0) sm[wave] = vmax;
        __syncthreads();
        if (tid == 0)
            ws[WS_PM + blk] = fmaxf(fmaxf(sm[0], sm[1]), fmaxf(sm[2], sm[3]));
    } else if (blk < 272) {
        int t = (blk - 256) * 256 + tid;       // 0..4095
        wh[t]                = (_Float16)f1W1[t];
        wh[H_W2 + t]         = (_Float16)f1W2[t];
        wh[H_NET + t]        = (_Float16)f2W1[t];
        wh[H_NET + H_W2 + t] = (_Float16)f2W2[t];
        if (t < 2048) {
            int j = t >> 5, k = t & 31;
            wh[H_W0 + t]        = (k < 5) ? (_Float16)f1W0[j * 5 + k] : (_Float16)0.0f;
            wh[H_W0 + 2048 + t] = (k < 5) ? (_Float16)f2W0[j * 5 + k] : (_Float16)0.0f;
        }
        if (t < 64) {
            wh[H_W3 + t]      = (_Float16)f1W3[t];
            wh[H_W3 + 64 + t] = (_Float16)f2W3[t];
        }
    } else if (blk == 272) {
        if (tid == 64) ws[WS_LAM] = 1.0f / (1.0f + expf(-sp[0]));
        if (tid <= 50) {
            int s = tid;
            ws[WS_CCS + s] = cospif((float)s / 50.0f);
            float acc = 0.0f;
            for (int a = 0; a <= 50; ++a) {
                float w;
                if (a == 0) w = 1.0f;
                else if ((a & 1) == 0) w = 2.0f / (1.0f - (float)(a * a));
                else continue;
                float l;
                if (s == 0) l = 0.5f;
                else {
                    int m = (a * s) % 100;
                    l = cospif((float)m / 50.0f);
                    if (s == 50) l *= 0.5f;
                }
                acc += l * 0.04f * w;
            }
            ws[WS_CCW + s] = acc;
        }
    } else if (blk < 305) {
        // zero step-2 accumulation targets: out[0..BB) and out[2BB..3BB)
        int t = (blk - 273) * 256 + tid;       // 0..8191
        out[t < BB ? t : BB + t] = 0.0f;
    } else {
        // zero step-1 accumulators A1 then A2 (contiguous 8192 floats)
        int t = (blk - 305) * 256 + tid;       // 0..8191
        ws[WS_A1 + t] = 0.0f;
    }
}

// Round-6 WIN structure (16 waves/group, grid 512, __launch_bounds__(256,2),
// LDS fragment-major weights, VGPR ~116 — NEVER squeeze via launch bounds).
// k_pre is eliminated WITHOUT the round-9 fence/last-block cost:
//   mode 0: identical hot loop; atomicAdd targets ws A1/A2 instead of out.
//   mode 1: prologue computes x/x2 inline (x = (1-lam)*xm + lam*A1, A1 final
//           by kernel-boundary ordering); u2 waves redundantly reduce
//           max(x2) over all 4096 items (16 coalesced float4-pairs + 6
//           shuffles, hidden under weight staging). No fence, no counter.
// Block b (0..511): group g = b>>2 (0..127), wave w = (b&3)*4+wloc (0..15).
// Group g owns items [(g&63)*64,+64) of net (g>=64 ? f2:f1). Wave w takes
// s = w, w+16, w+32 [, w+48 if w<3]; the w==15 f1 wave in mode 1 computes
// out_first in its dead 4th slot. One atomicAdd per item per wave.
__global__ __launch_bounds__(256, 2) void k_int(
    int mode, float* __restrict__ ws, const float* __restrict__ h_,
    const float* __restrict__ f1b0, const float* __restrict__ f1b1,
    const float* __restrict__ f1b2, const float* __restrict__ f1b3,
    const float* __restrict__ f1Wf,
    const float* __restrict__ f2b0, const float* __restrict__ f2b1,
    const float* __restrict__ f2b2, const float* __restrict__ f2b3,
    const float* __restrict__ f2Wf,
    float* __restrict__ out)
{
    __shared__ _Float16 act[4 * 64 * 64];   // 32 KB: per-wave slices
    __shared__ _Float16 w0f[4 * 16 * 8];    // 1 KB  : L0 frags (q==0 only)
    __shared__ _Float16 w1f[512 * 8];       // 8 KB  : L1 frags, frag-major
    __shared__ _Float16 w2f[512 * 8];       // 8 KB  : L2 frags, frag-major
    __shared__ float bl[192];               // biases: [layer*64 + feat]

    const int tid = threadIdx.x;
    const int blk = blockIdx.x;
    const int wloc = tid >> 6;
    const int lane = tid & 63;
    const int lo = lane & 15, q = lane >> 4;

    const int g = blk >> 2;               // 0..127
    const int w = (blk & 3) * 4 + wloc;   // 0..15
    const bool u2 = (g >= 64);
    const int base = (g & 63) << 6;
    const bool of_wave = (mode != 0) && (!u2) && (w == 15);

    const float* xm = ws + WS_XM;
    const float* a1p = ws + WS_A1;
    const float* a2p = ws + WS_A2;
    const _Float16* wh = (const _Float16*)(ws + WS_H);
    const float lam = ws[WS_LAM];
    const float oml = 1.0f - lam;

    const _Float16* W0h = wh + H_W0 + (u2 ? 2048 : 0);
    const _Float16* W1h = wh + (u2 ? H_NET : 0);
    const _Float16* W2h = W1h + H_W2;
    const _Float16* W3h = wh + H_W3 + (u2 ? 64 : 0);
    const float* B0 = u2 ? f2b0 : f1b0;
    const float* B1 = u2 ? f2b1 : f1b1;
    const float* B2 = u2 ? f2b2 : f1b2;
    const float* B3 = u2 ? f2b3 : f1b3;
    const float* WF = u2 ? f2Wf : f1Wf;
    const float p0 = u2 ? 1.5f : 1.1f;
    const float p1 = u2 ? 2.0f : 1.1f;
    const float p2 = u2 ? 2.5f : 1.5f;
    const float p3 = u2 ? 3.0f : 2.0f;
    const float p4 = u2 ? 3.5f : 2.5f;

    // ---- stage weights -> LDS, fragment-major (f = (m*2+kb)*64 + lane) ----
    #pragma unroll
    for (int f = tid; f < 512; f += 256) {
        int fm = f >> 7, fkb = (f >> 6) & 1, fl = f & 63;
        int flo = fl & 15, fq = fl >> 4;
        *(half8v*)(w1f + f * 8) =
            *(const half8v*)(W1h + (16 * fm + flo) * 64 + fkb * 32 + fq * 8);
        *(half8v*)(w2f + f * 8) =
            *(const half8v*)(W2h + (16 * fm + flo) * 64 + fkb * 32 + fq * 8);
    }
    if (tid < 64) {
        int fm = tid >> 4, flo = tid & 15;
        *(half8v*)(w0f + tid * 8) = *(const half8v*)(W0h + (16 * fm + flo) * 32);
    }
    if (tid < 192)
        bl[tid] = (tid < 64) ? B0[tid] : (tid < 128) ? B1[tid - 64] : B2[tid - 128];

    // ---- small per-lane pins (while staging is in flight) ----
    half4v w3r[4];
    #pragma unroll
    for (int m = 0; m < 4; ++m)
        w3r[m] = *(const half4v*)(W3h + 16 * m + 4 * q);
    const float B3s = B3[0];
    const float wf0 = WF[0], wf1 = WF[1], wf2 = WF[2], wf3 = WF[3], wf4 = WF[4];

    half8v zf;                            // zero fragment (shared)
    #pragma unroll
    for (int t2 = 0; t2 < 8; ++t2) zf[t2] = (_Float16)0.0f;

    float xr_r[4], x2_r[4];
    half8v tpl[4];                        // pre-packed B template (h in halfs)
    #pragma unroll
    for (int n = 0; n < 4; ++n) {
        int idx = base + 16 * n + lo;
        float xmv = xm[idx];
        if (mode == 0) {
            xr_r[n] = oml * xmv;
        } else {
            float a = u2 ? a2p[idx] : a1p[idx];
            xr_r[n] = fmaf(lam, a, oml * xmv);       // x or x2 inline
        }
        float4 h4 = ((const float4*)h_)[idx];
        half8v e = zf;
        e[1] = (_Float16)h4.x; e[2] = (_Float16)h4.y;
        e[3] = (_Float16)h4.z; e[4] = (_Float16)h4.w;
        tpl[n] = (q == 0) ? e : zf;
        x2_r[n] = 0.0f;
    }
    if (of_wave) {
        #pragma unroll
        for (int n = 0; n < 4; ++n) {
            int idx = base + 16 * n + lo;
            x2_r[n] = fmaf(lam, a2p[idx], oml * xm[idx]);
        }
    }

    float xmax = 0.0f;
    if (u2) {
        if (mode) {
            // redundant per-wave max(x2) over all 4096 items (coalesced)
            float v = -1e30f;
            #pragma unroll 4
            for (int j = 0; j < 16; ++j) {
                int i = j * 256 + lane * 4;
                float4 xm4 = *(const float4*)(xm + i);
                float4 a24 = *(const float4*)(a2p + i);
                v = fmaxf(v, fmaf(lam, a24.x, oml * xm4.x));
                v = fmaxf(v, fmaf(lam, a24.y, oml * xm4.y));
                v = fmaxf(v, fmaf(lam, a24.z, oml * xm4.z));
                v = fmaxf(v, fmaf(lam, a24.w, oml * xm4.w));
            }
            #pragma unroll
            for (int off = 32; off > 0; off >>= 1) v = fmaxf(v, __shfl_xor(v, off, 64));
            xmax = v + 10.0f;
        } else {
            const float* pm = ws + WS_PM;
            float v = fmaxf(fmaxf(pm[lane], pm[lane + 64]),
                            fmaxf(pm[lane + 128], pm[lane + 192]));
            #pragma unroll
            for (int off = 32; off > 0; off >>= 1) v = fmaxf(v, __shfl_xor(v, off, 64));
            xmax = oml * v + 10.0f;
        }
    }

    __syncthreads();                      // weights/biases staged

    _Float16* actw = act + (wloc << 12);  // private 4096-half slice
    const int np = (w < 3 || of_wave) ? 4 : 3;
    float acc = 0.0f;

    #pragma clang loop unroll(disable)
    for (int p = 0; p < np; ++p) {
        const bool of_iter = of_wave && (p == 3);
        float t = 0.0f, ccw_s = 0.0f;
        if (!of_iter) {
            int s = w + 16 * p;                     // <= 50 by construction
            t = (ws[WS_CCS + s] + 1.0f) * 0.5f;
            ccw_s = ws[WS_CCW + s];
        }

        // build B-operand for layer 0 from template (q==0 lanes carry k=0..4)
        half8v Bf0[4];
        #pragma unroll
        for (int n = 0; n < 4; ++n) {
            float xin;
            if (of_iter) xin = x2_r[n];
            else if (u2) xin = fmaf(t, xmax - xr_r[n], xr_r[n]);
            else         xin = xr_r[n] * t;
            half8v b = tpl[n];
            b[0] = (_Float16)((q == 0) ? xin : 0.0f);
            Bf0[n] = b;
        }

        // ---- layer 0: A-frag from LDS (broadcast reads, q==0 rows only) ----
        #pragma unroll
        for (int m = 0; m < 4; ++m) {
            half8v a0 = (q == 0) ? *(const half8v*)(w0f + (m * 16 + lo) * 8) : zf;
            float4v b0 = *(const float4v*)(bl + 16 * m + 4 * q);
            #pragma unroll
            for (int n = 0; n < 4; ++n) {
                float4v c = __builtin_amdgcn_mfma_f32_16x16x32_f16(a0, Bf0[n], b0, 0, 0, 0);
                *(half4v*)(actw + swz(16 * n + lo, 2 * m + (q >> 1)) + 4 * (q & 1)) = pk_relu4(c);
            }
        }

        // ---- layer 1: A-frags lane-consecutive from LDS ----
        {
            half8v Bf[2][4];
            #pragma unroll
            for (int kb = 0; kb < 2; ++kb)
                #pragma unroll
                for (int n = 0; n < 4; ++n)
                    Bf[kb][n] = *(const half8v*)(actw + swz(16 * n + lo, 4 * kb + q));
            #pragma unroll
            for (int m = 0; m < 4; ++m) {
                half8v a10 = *(const half8v*)(w1f + ((m * 2 + 0) * 64 + lane) * 8);
                half8v a11 = *(const half8v*)(w1f + ((m * 2 + 1) * 64 + lane) * 8);
                float4v b1 = *(const float4v*)(bl + 64 + 16 * m + 4 * q);
                #pragma unroll
                for (int n = 0; n < 4; ++n) {
                    float4v c = __builtin_amdgcn_mfma_f32_16x16x32_f16(a10, Bf[0][n], b1, 0, 0, 0);
                    c = __builtin_amdgcn_mfma_f32_16x16x32_f16(a11, Bf[1][n], c, 0, 0, 0);
                    *(half4v*)(actw + swz(16 * n + lo, 2 * m + (q >> 1)) + 4 * (q & 1)) = pk_relu4(c);
                }
            }
        }

        // ---- layer 2 with fused W3-dot ----
        float part[4] = {0.0f, 0.0f, 0.0f, 0.0f};
        {
            half8v Bf[2][4];
            #pragma unroll
            for (int kb = 0; kb < 2; ++kb)
                #pragma unroll
                for (int n = 0; n < 4; ++n)
                    Bf[kb][n] = *(const half8v*)(actw + swz(16 * n + lo, 4 * kb + q));
            #pragma unroll
            for (int m = 0; m < 4; ++m) {
                half8v a20 = *(const half8v*)(w2f + ((m * 2 + 0) * 64 + lane) * 8);
                half8v a21 = *(const half8v*)(w2f + ((m * 2 + 1) * 64 + lane) * 8);
                float4v b2 = *(const float4v*)(bl + 128 + 16 * m + 4 * q);
                #pragma unroll
                for (int n = 0; n < 4; ++n) {
                    float4v c = __builtin_amdgcn_mfma_f32_16x16x32_f16(a20, Bf[0][n], b2, 0, 0, 0);
                    c = __builtin_amdgcn_mfma_f32_16x16x32_f16(a21, Bf[1][n], c, 0, 0, 0);
                    #pragma unroll
                    for (int e = 0; e < 4; ++e)
                        part[n] = fmaf((float)w3r[m][e], fmaxf(c[e], 0.0f), part[n]);
                }
            }
        }

        // complete each row's dot across quads; lane keeps its own row (=lane)
        #pragma unroll
        for (int n = 0; n < 4; ++n) {
            part[n] += __shfl_xor(part[n], 16, 64);
            part[n] += __shfl_xor(part[n], 32, 64);
        }
        float y = B3s + (q == 0 ? part[0] : q == 1 ? part[1] : q == 2 ? part[2] : part[3]);

        float val = tail5(y, p0, p1, p2, p3, p4, wf0, wf1, wf2, wf3, wf4);

        if (of_iter) out[BB + base + lane] = val;
        else         acc = fmaf(ccw_s, val, acc);
    }

    // ---- per-item epilogue: lane owns item base+lane (row 16q+lo == lane) ----
    const float x_l = (q == 0 ? xr_r[0] : q == 1 ? xr_r[1] : q == 2 ? xr_r[2] : xr_r[3]);
    if (mode == 0) {
        if (!u2) atomicAdd(ws + WS_A1 + base + lane, acc * x_l * 0.5f);
        else     atomicAdd(ws + WS_A2 + base + lane, acc * (xmax - x_l) * 0.5f * INV_ALPHA);
    } else {
        if (!u2) atomicAdd(out + base + lane, acc * x_l * 0.5f);
        else     atomicAdd(out + 2 * BB + base + lane,
                           acc * (xmax - x_l) * 0.5f * INV_ALPHA);
    }
}

extern "C" void kernel_launch(void* const* d_in, const int* in_sizes, int n_in,
                              void* d_out, int out_size, void* d_ws, size_t ws_size,
                              hipStream_t stream) {
    const float* x_  = (const float*)d_in[0];
    const float* h_  = (const float*)d_in[1];
    const float* lw  = (const float*)d_in[2];
    const float* sp  = (const float*)d_in[3];
    const float* f1W0 = (const float*)d_in[4];   const float* f1b0 = (const float*)d_in[5];
    const float* f1W1 = (const float*)d_in[6];   const float* f1b1 = (const float*)d_in[7];
    const float* f1W2 = (const float*)d_in[8];   const float* f1b2 = (const float*)d_in[9];
    const float* f1W3 = (const float*)d_in[10];  const float* f1b3 = (const float*)d_in[11];
    const float* f1Wf = (const float*)d_in[12];
    const float* f2W0 = (const float*)d_in[13];  const float* f2b0 = (const float*)d_in[14];
    const float* f2W1 = (const float*)d_in[15];  const float* f2b1 = (const float*)d_in[16];
    const float* f2W2 = (const float*)d_in[17];  const float* f2b2 = (const float*)d_in[18];
    const float* f2W3 = (const float*)d_in[19];  const float* f2b3 = (const float*)d_in[20];
    const float* f2Wf = (const float*)d_in[21];
    float* out = (float*)d_out;
    float* ws  = (float*)d_ws;

    k_setup<<<337, 256, 0, stream>>>(x_, lw, sp,
                                     f1W0, f1W1, f1W2, f1W3,
                                     f2W0, f2W1, f2W2, f2W3, ws, out);
    k_int<<<512, 256, 0, stream>>>(0, ws, h_,
        f1b0, f1b1, f1b2, f1b3, f1Wf, f2b0, f2b1, f2b2, f2b3, f2Wf, out);
    k_int<<<512, 256, 0, stream>>>(1, ws, h_,
        f1b0, f1b1, f1b2, f1b3, f1Wf, f2b0, f2b1, f2b2, f2b3, f2Wf, out);
}